// Round 2
// 1107.460 us; speedup vs baseline: 1.2177x; 1.2177x over previous
//
#include <hip/hip_runtime.h>
#include <hip/hip_bf16.h>
#include <cstdint>
#include <cstddef>

// B=4, L=2048, H=2048, NH=16, HD=128. Inputs/outputs fp32 (confirmed round 5).
// Round 6: gemm_qkv A-path converts fp32->bf16 at staging (pure bf16 inner loop);
// XOR chunk swizzle (slot = j ^ (r&7)) on As/Bs in both GEMMs -> 2-way (free) reads.
// Round 7: same XOR chunk swizzle applied to flash_kernel's Qs/Ks/Vt (was 16-way
// conflicted on every ds_read_b128: row stride 256B/128B == 0 mod 128B bank period;
// SQ_LDS_BANK_CONFLICT 1.03e8 ~= 27% of kernel cycles). ASYNC16 keeps LDS dest
// linear; global source chunk is pre-swizzled; reads XOR the chunk with (row&7).
// Ps (stride 72) already 2-way-free, untouched. Workspace exactly 128 MB.
// Round 8: resubmit of round 7 unchanged (container infra failure, no counters).

typedef __attribute__((ext_vector_type(4))) float f32x4;
typedef __attribute__((ext_vector_type(8))) short bf16x8;
typedef __hip_bfloat16 bf16;

#define ASYNC16(lds, g)                                                                  \
  __builtin_amdgcn_global_load_lds((const __attribute__((address_space(1))) void*)(g),   \
                                   (__attribute__((address_space(3))) void*)(lds), 16, 0, 0)

__device__ __forceinline__ float b2f(bf16 v) { return __bfloat162float(v); }
__device__ __forceinline__ bf16 f2b(float v) { return __float2bfloat16(v); }
__device__ __forceinline__ short f2bs(float f) {
  bf16 h = __float2bfloat16(f);
  return __builtin_bit_cast(short, h);
}
__device__ __forceinline__ bf16x8 pack8(f32x4 a, f32x4 b) {
  bf16x8 r;
#pragma unroll
  for (int t = 0; t < 4; ++t) r[t] = f2bs(a[t]);
#pragma unroll
  for (int t = 0; t < 4; ++t) r[4 + t] = f2bs(b[t]);
  return r;
}

// ---------------------------------------------------------------------------
// Transpose+convert fp32 (R x C) -> bf16 (C x R).
__global__ void transpose_conv(const float* __restrict__ src, bf16* __restrict__ dst,
                               int R, int C) {
  __shared__ float tile[32][33];
  int bx = blockIdx.x * 32, by = blockIdx.y * 32;
  int tx = threadIdx.x, ty = threadIdx.y;
  for (int i = ty; i < 32; i += 8) tile[i][tx] = src[(size_t)(by + i) * C + bx + tx];
  __syncthreads();
  for (int i = ty; i < 32; i += 8) dst[(size_t)(bx + i) * R + by + tx] = f2b(tile[tx][i]);
}

// ---------------------------------------------------------------------------
// QKV GEMM: C(8192,6144) = x(8192,2048) * WqkvT(6144,2048)^T. 128x128 tile, BK=64.
// A: global fp32 -> VGPR -> pack bf16 -> ds_write_b128 (swizzled slot).
// B: ASYNC16 with swizzled GLOBAL source chunk. Reads use slot (q ^ (r&7)).
__global__ __launch_bounds__(256) void gemm_qkv(const float* __restrict__ Ax,
                                                const bf16* __restrict__ Bt,
                                                const float* __restrict__ biasf,
                                                bf16* __restrict__ Qg, bf16* __restrict__ Kg,
                                                bf16* __restrict__ Vg) {
  __shared__ alignas(16) bf16 As[128 * 64];  // 16 KB
  __shared__ alignas(16) bf16 Bs[128 * 64];  // 16 KB
  const int K_ = 2048;
  int tid = threadIdx.x, lane = tid & 63, w = tid >> 6;
  int lr = lane & 15, hi = lane >> 4;
  int wm = (w >> 1) * 64, wn = (w & 1) * 64;
  int m0 = blockIdx.y * 128, n0 = blockIdx.x * 128;
  f32x4 acc[4][4];
#pragma unroll
  for (int im = 0; im < 4; ++im)
#pragma unroll
    for (int in = 0; in < 4; ++in) acc[im][in] = (f32x4){0.f, 0.f, 0.f, 0.f};

  for (int k0 = 0; k0 < K_; k0 += 64) {
    __syncthreads();
    // A: 1024 bf16-chunks (16B = 8 elems). chunk c: row r=c>>3, chunk j=c&7.
#pragma unroll
    for (int i = 0; i < 4; ++i) {
      int c = tid + 256 * i;
      int r = c >> 3, j = c & 7;
      const float* gp = Ax + (size_t)(m0 + r) * K_ + k0 + j * 8;
      f32x4 a0 = *(const f32x4*)gp;
      f32x4 a1 = *(const f32x4*)(gp + 4);
      *(bf16x8*)((char*)As + r * 128 + ((j ^ (r & 7)) * 16)) = pack8(a0, a1);
    }
    // B: ASYNC16, swizzle applied to the global source chunk index.
#pragma unroll
    for (int i = 0; i < 4; ++i) {
      int c = tid + 256 * i;
      int r = c >> 3, j = c & 7, jg = j ^ (r & 7);
      ASYNC16((char*)Bs + c * 16, (const char*)(Bt + (size_t)(n0 + r) * K_ + k0 + jg * 8));
    }
    __syncthreads();

#pragma unroll
    for (int ks = 0; ks < 2; ++ks) {
      bf16x8 afr[4], bfr[4];
#pragma unroll
      for (int im = 0; im < 4; ++im) {
        int r = wm + 16 * im + lr;
        afr[im] = *(const bf16x8*)((const char*)As + r * 128 + (((ks * 4 + hi) ^ (r & 7)) * 16));
      }
#pragma unroll
      for (int in = 0; in < 4; ++in) {
        int r = wn + 16 * in + lr;
        bfr[in] = *(const bf16x8*)((const char*)Bs + r * 128 + (((ks * 4 + hi) ^ (r & 7)) * 16));
      }
#pragma unroll
      for (int im = 0; im < 4; ++im)
#pragma unroll
        for (int in = 0; in < 4; ++in)
          acc[im][in] =
              __builtin_amdgcn_mfma_f32_16x16x32_bf16(afr[im], bfr[in], acc[im][in], 0, 0, 0);
    }
  }

  // Epilogue: col c -> which=c>>11; of cc=c&2047: h=cc&15, d=cc>>4.
#pragma unroll
  for (int im = 0; im < 4; ++im) {
    int mrow = m0 + wm + 16 * im + 4 * hi;
#pragma unroll
    for (int in = 0; in < 4; ++in) {
      int c = n0 + wn + 16 * in + lr;
      int which = c >> 11, cc = c & 2047;
      int hh = cc & 15, d = cc >> 4;
      float bv = biasf[c];
#pragma unroll
      for (int j = 0; j < 4; ++j) {
        int m = mrow + j;
        int bb = m >> 11, l = m & 2047;
        int bh = bb * 16 + hh;
        bf16 hv = f2b(acc[im][in][j] + bv);
        if (which == 0)
          Qg[((size_t)bh * 2048 + l) * 128 + d] = hv;
        else if (which == 1)
          Kg[((size_t)bh * 2048 + l) * 128 + d] = hv;
        else
          Vg[((size_t)bh * 128 + d) * 2048 + l] = hv;
      }
    }
  }
}

// ---------------------------------------------------------------------------
// FC2 GEMM: Out(8192,2048) = Y(8192,2048) * Wfc2T(2048,2048)^T, bias+SiLU, fp32 out.
// Both operands bf16 in ws -> ASYNC16 with swizzled source; swizzled reads.
__global__ __launch_bounds__(256) void gemm_fc2(const bf16* __restrict__ A,
                                                const bf16* __restrict__ Bt,
                                                const float* __restrict__ biasf,
                                                float* __restrict__ Out) {
  __shared__ alignas(16) bf16 As[128 * 64];
  __shared__ alignas(16) bf16 Bs[128 * 64];
  const int K_ = 2048;
  int tid = threadIdx.x, lane = tid & 63, w = tid >> 6;
  int lr = lane & 15, hi = lane >> 4;
  int wm = (w >> 1) * 64, wn = (w & 1) * 64;
  int m0 = blockIdx.y * 128, n0 = blockIdx.x * 128;
  f32x4 acc[4][4];
#pragma unroll
  for (int im = 0; im < 4; ++im)
#pragma unroll
    for (int in = 0; in < 4; ++in) acc[im][in] = (f32x4){0.f, 0.f, 0.f, 0.f};

  for (int k0 = 0; k0 < K_; k0 += 64) {
    __syncthreads();
#pragma unroll
    for (int i = 0; i < 4; ++i) {
      int c = tid + 256 * i;
      int r = c >> 3, j = c & 7, jg = j ^ (r & 7);
      ASYNC16((char*)As + c * 16, (const char*)(A + (size_t)(m0 + r) * K_ + k0 + jg * 8));
    }
#pragma unroll
    for (int i = 0; i < 4; ++i) {
      int c = tid + 256 * i;
      int r = c >> 3, j = c & 7, jg = j ^ (r & 7);
      ASYNC16((char*)Bs + c * 16, (const char*)(Bt + (size_t)(n0 + r) * K_ + k0 + jg * 8));
    }
    __syncthreads();
#pragma unroll
    for (int ks = 0; ks < 2; ++ks) {
      bf16x8 afr[4], bfr[4];
#pragma unroll
      for (int im = 0; im < 4; ++im) {
        int r = wm + 16 * im + lr;
        afr[im] = *(const bf16x8*)((const char*)As + r * 128 + (((ks * 4 + hi) ^ (r & 7)) * 16));
      }
#pragma unroll
      for (int in = 0; in < 4; ++in) {
        int r = wn + 16 * in + lr;
        bfr[in] = *(const bf16x8*)((const char*)Bs + r * 128 + (((ks * 4 + hi) ^ (r & 7)) * 16));
      }
#pragma unroll
      for (int im = 0; im < 4; ++im)
#pragma unroll
        for (int in = 0; in < 4; ++in)
          acc[im][in] =
              __builtin_amdgcn_mfma_f32_16x16x32_bf16(afr[im], bfr[in], acc[im][in], 0, 0, 0);
    }
  }

#pragma unroll
  for (int im = 0; im < 4; ++im) {
#pragma unroll
    for (int in = 0; in < 4; ++in) {
      int c = n0 + wn + 16 * in + lr;
      float bv = biasf[c];
#pragma unroll
      for (int j = 0; j < 4; ++j) {
        int m = m0 + wm + 16 * im + 4 * hi + j;
        float z = acc[im][in][j] + bv;
        Out[(size_t)m * 2048 + c] = z / (1.f + __expf(-z));
      }
    }
  }
}

// ---------------------------------------------------------------------------
// Rotary in-place on Q,K head layout. Pair (d, d+64), angle col = d*16+h. fp32 cos/sin.
__global__ void rotary_kernel(bf16* __restrict__ Qg, bf16* __restrict__ Kg,
                              const float* __restrict__ cosp, const float* __restrict__ sinp) {
  int idx = blockIdx.x * 256 + threadIdx.x;  // B*NH*L*64 = 8388608
  int d = idx & 63;
  int l = (idx >> 6) & 2047;
  int bh = idx >> 17;
  int h = bh & 15;
  size_t base = ((size_t)bh * 2048 + l) * 128;
  int ang = l * 1024 + d * 16 + h;
  float c = cosp[ang], s = sinp[ang];
  float q1 = b2f(Qg[base + d]), q2 = b2f(Qg[base + d + 64]);
  Qg[base + d] = f2b(q1 * c + q2 * s);
  Qg[base + d + 64] = f2b(-q1 * s + q2 * c);
  float k1 = b2f(Kg[base + d]), k2 = b2f(Kg[base + d + 64]);
  Kg[base + d] = f2b(k1 * c + k2 * s);
  Kg[base + d + 64] = f2b(-k1 * s + k2 * c);
}

// ---------------------------------------------------------------------------
// Causal flash attention. Round 7: XOR chunk swizzle on Qs/Ks/Vt.
// LDS slot (r, j) holds global chunk (r, j ^ (r&7)); every ds_read_b128 XORs its
// chunk index with (row&7). 16 lanes/group now hit 8 distinct bank-quads (2-way,
// free) instead of 1 (16-way).
__global__ __launch_bounds__(256) void flash_kernel(const bf16* __restrict__ Qg,
                                                    const bf16* __restrict__ Kg,
                                                    const bf16* __restrict__ Vg,
                                                    bf16* __restrict__ Y) {
  __shared__ alignas(16) bf16 Qs[64 * 128];
  __shared__ alignas(16) bf16 Ks[64 * 128];
  __shared__ alignas(16) bf16 Vt[128 * 64];
  __shared__ alignas(16) bf16 Ps[4 * 16 * 72];
  int tid = threadIdx.x, lane = tid & 63, w = tid >> 6;
  int lr = lane & 15, hi = lane >> 4;
  int it = 31 - (int)blockIdx.x;
  int bh = blockIdx.y;
  int b = bh >> 4, h = bh & 15;
  int q0 = it * 64;
  const bf16* Qb = Qg + (size_t)bh * 2048 * 128;
  const bf16* Kb = Kg + (size_t)bh * 2048 * 128;
  const bf16* Vb = Vg + (size_t)bh * 128 * 2048;
  const float NEG = -1.0e30f;

#pragma unroll
  for (int i = 0; i < 4; ++i) {
    int c = tid + 256 * i;
    int r = c >> 4, j = c & 15, jg = j ^ (r & 7);
    ASYNC16((char*)Qs + c * 16, (const char*)(Qb + (size_t)(q0 + r) * 128 + jg * 8));
  }

  f32x4 o[8];
#pragma unroll
  for (int i = 0; i < 8; ++i) o[i] = (f32x4){0.f, 0.f, 0.f, 0.f};
  float m_i[4], l_i[4];
#pragma unroll
  for (int j = 0; j < 4; ++j) { m_i[j] = NEG; l_i[j] = 0.f; }
  const float scale = 0.08838834764831845f;  // 1/sqrt(128)

  for (int jt = 0; jt <= it; ++jt) {
    int k0 = jt * 64;
    __syncthreads();
#pragma unroll
    for (int i = 0; i < 4; ++i) {
      int c = tid + 256 * i;
      int r = c >> 4, j = c & 15, jg = j ^ (r & 7);
      ASYNC16((char*)Ks + c * 16, (const char*)(Kb + (size_t)(k0 + r) * 128 + jg * 8));
    }
#pragma unroll
    for (int i = 0; i < 4; ++i) {
      int c = tid + 256 * i;
      int r = c >> 3, j = c & 7, jg = j ^ (r & 7);
      ASYNC16((char*)Vt + c * 16, (const char*)(Vb + (size_t)r * 2048 + k0 + jg * 8));
    }
    __syncthreads();

    f32x4 sacc[4];
#pragma unroll
    for (int in = 0; in < 4; ++in) sacc[in] = (f32x4){0.f, 0.f, 0.f, 0.f};
#pragma unroll
    for (int ks = 0; ks < 4; ++ks) {
      int ar = 16 * w + lr;
      bf16x8 a = *(const bf16x8*)((const char*)Qs + ar * 256 + (((ks * 4 + hi) ^ (ar & 7)) * 16));
#pragma unroll
      for (int in = 0; in < 4; ++in) {
        int br = 16 * in + lr;
        bf16x8 bb =
            *(const bf16x8*)((const char*)Ks + br * 256 + (((ks * 4 + hi) ^ (br & 7)) * 16));
        sacc[in] = __builtin_amdgcn_mfma_f32_16x16x32_bf16(a, bb, sacc[in], 0, 0, 0);
      }
    }

    bool diag = (jt == it);
#pragma unroll
    for (int j = 0; j < 4; ++j) {
      float mx = NEG;
#pragma unroll
      for (int in = 0; in < 4; ++in) {
        float s = sacc[in][j] * scale;
        if (diag) {
          int qg = 16 * w + 4 * hi + j;
          int kg = 16 * in + lr;
          if (kg > qg) s = NEG;
        }
        sacc[in][j] = s;
        mx = fmaxf(mx, s);
      }
#pragma unroll
      for (int off = 1; off < 16; off <<= 1) mx = fmaxf(mx, __shfl_xor(mx, off));
      float mnew = fmaxf(m_i[j], mx);
      float alpha = __expf(m_i[j] - mnew);
      float rs = 0.f;
#pragma unroll
      for (int in = 0; in < 4; ++in) {
        float p = __expf(sacc[in][j] - mnew);
        sacc[in][j] = p;
        rs += p;
      }
#pragma unroll
      for (int off = 1; off < 16; off <<= 1) rs += __shfl_xor(rs, off);
      l_i[j] = alpha * l_i[j] + rs;
      m_i[j] = mnew;
#pragma unroll
      for (int inp = 0; inp < 8; ++inp) o[inp][j] *= alpha;
    }

#pragma unroll
    for (int j = 0; j < 4; ++j)
#pragma unroll
      for (int in = 0; in < 4; ++in)
        Ps[w * 1152 + (4 * hi + j) * 72 + 16 * in + lr] = f2b(sacc[in][j]);
    __syncthreads();

#pragma unroll
    for (int ko = 0; ko < 2; ++ko) {
      bf16x8 a = *(const bf16x8*)((const char*)Ps + (w * 1152 + lr * 72 + ko * 32 + hi * 8) * 2);
#pragma unroll
      for (int inp = 0; inp < 8; ++inp) {
        int br = 16 * inp + lr;
        bf16x8 bb =
            *(const bf16x8*)((const char*)Vt + br * 128 + (((ko * 4 + hi) ^ (br & 7)) * 16));
        o[inp] = __builtin_amdgcn_mfma_f32_16x16x32_bf16(a, bb, o[inp], 0, 0, 0);
      }
    }
  }

#pragma unroll
  for (int j = 0; j < 4; ++j) {
    int qg = q0 + 16 * w + 4 * hi + j;
    float inv = 1.f / l_i[j];
    size_t rowb = ((size_t)(b * 2048 + qg)) * 2048 + h * 128;
#pragma unroll
    for (int inp = 0; inp < 8; ++inp) {
      int dd = 16 * inp + lr;
      Y[rowb + dd] = f2b(o[inp][j] * inv);
    }
  }
}

// ---------------------------------------------------------------------------
extern "C" void kernel_launch(void* const* d_in, const int* in_sizes, int n_in,
                              void* d_out, int out_size, void* d_ws, size_t ws_size,
                              hipStream_t stream) {
  const float* x    = (const float*)d_in[0];  // 8192 x 2048
  const float* Wqkv = (const float*)d_in[1];  // 2048 x 6144
  const float* bqkv = (const float*)d_in[2];  // 6144
  const float* Wfc2 = (const float*)d_in[3];  // 2048 x 2048
  const float* bfc2 = (const float*)d_in[4];  // 2048
  const float* cosp = (const float*)d_in[5];  // 2048 x 1024
  const float* sinp = (const float*)d_in[6];  // 2048 x 1024
  float* out = (float*)d_out;

  // Workspace (bf16 elems), exactly 67,108,864 = 128 MB:
  //   [0, 16.78M):      Yg (flash out). WqkvT [0,12.58M) aliased pre-flash.
  //   [16.78M, 33.55M): Qg. Wfc2T [+0,+4.19M) aliased post-flash.
  //   [33.55M, 50.33M): Kg.
  //   [50.33M, 67.11M): Vg [bh][128][l].
  bf16* ws = (bf16*)d_ws;
  bf16* Yg    = ws;
  bf16* WqkvT = ws;
  bf16* Qg    = ws + 16777216;
  bf16* Wfc2T = ws + 16777216;
  bf16* Kg    = ws + 33554432;
  bf16* Vg    = ws + 50331648;

  transpose_conv<<<dim3(192, 64), dim3(32, 8), 0, stream>>>(Wqkv, WqkvT, 2048, 6144);
  gemm_qkv<<<dim3(48, 64), 256, 0, stream>>>(x, WqkvT, bqkv, Qg, Kg, Vg);
  rotary_kernel<<<32768, 256, 0, stream>>>(Qg, Kg, cosp, sinp);
  flash_kernel<<<dim3(32, 64), 256, 0, stream>>>(Qg, Kg, Vg, Yg);
  transpose_conv<<<dim3(64, 64), dim3(32, 8), 0, stream>>>(Wfc2, Wfc2T, 2048, 2048);
  gemm_fc2<<<dim3(16, 64), 256, 0, stream>>>(Yg, Wfc2T, bfc2, out);
}

// Round 3
// 1032.075 us; speedup vs baseline: 1.3067x; 1.0730x over previous
//
#include <hip/hip_runtime.h>
#include <hip/hip_bf16.h>
#include <cstdint>
#include <cstddef>

// B=4, L=2048, H=2048, NH=16, HD=128. Inputs/outputs fp32.
// Round 7: XOR chunk swizzle on flash Qs/Ks/Vt (bank conflicts 1.03e8 -> ~0),
//          flash 612 -> ~370 us, total 1349 -> 1107 us. CONFIRMED.
// Round 9: gemm_qkv was 527 us @ 391 TF, MfmaUtil 16.7% — A-path staged fp32
//          through VALU pack8 + ds_write inside the K-loop. Now: x is
//          pre-converted to bf16 ONCE (conv_bf16, parked in d_out which is dead
//          until gemm_fc2), and gemm_qkv stages BOTH operands via ASYNC16,
//          structurally identical to gemm_fc2 (the ~900 TF m97 structure).
// Workspace exactly 128 MB; x_bf16 lives in d_out (33.5 of 67 MB).

typedef __attribute__((ext_vector_type(4))) float f32x4;
typedef __attribute__((ext_vector_type(8))) short bf16x8;
typedef __hip_bfloat16 bf16;

#define ASYNC16(lds, g)                                                                  \
  __builtin_amdgcn_global_load_lds((const __attribute__((address_space(1))) void*)(g),   \
                                   (__attribute__((address_space(3))) void*)(lds), 16, 0, 0)

__device__ __forceinline__ float b2f(bf16 v) { return __bfloat162float(v); }
__device__ __forceinline__ bf16 f2b(float v) { return __float2bfloat16(v); }
__device__ __forceinline__ short f2bs(float f) {
  bf16 h = __float2bfloat16(f);
  return __builtin_bit_cast(short, h);
}
__device__ __forceinline__ bf16x8 pack8(f32x4 a, f32x4 b) {
  bf16x8 r;
#pragma unroll
  for (int t = 0; t < 4; ++t) r[t] = f2bs(a[t]);
#pragma unroll
  for (int t = 0; t < 4; ++t) r[4 + t] = f2bs(b[t]);
  return r;
}

// ---------------------------------------------------------------------------
// Elementwise fp32 -> bf16, 8 elems/thread, fully coalesced.
__global__ void conv_bf16(const float* __restrict__ src, bf16* __restrict__ dst) {
  size_t i = ((size_t)blockIdx.x * 256 + threadIdx.x) * 8;
  f32x4 a0 = *(const f32x4*)(src + i);
  f32x4 a1 = *(const f32x4*)(src + i + 4);
  *(bf16x8*)(dst + i) = pack8(a0, a1);
}

// ---------------------------------------------------------------------------
// Transpose+convert fp32 (R x C) -> bf16 (C x R).
__global__ void transpose_conv(const float* __restrict__ src, bf16* __restrict__ dst,
                               int R, int C) {
  __shared__ float tile[32][33];
  int bx = blockIdx.x * 32, by = blockIdx.y * 32;
  int tx = threadIdx.x, ty = threadIdx.y;
  for (int i = ty; i < 32; i += 8) tile[i][tx] = src[(size_t)(by + i) * C + bx + tx];
  __syncthreads();
  for (int i = ty; i < 32; i += 8) dst[(size_t)(bx + i) * R + by + tx] = f2b(tile[tx][i]);
}

// ---------------------------------------------------------------------------
// QKV GEMM: C(8192,6144) = xb(8192,2048) * WqkvT(6144,2048)^T. 128x128, BK=64.
// Both operands bf16 -> ASYNC16 with swizzled global source; swizzled reads.
__global__ __launch_bounds__(256) void gemm_qkv(const bf16* __restrict__ A,
                                                const bf16* __restrict__ Bt,
                                                const float* __restrict__ biasf,
                                                bf16* __restrict__ Qg, bf16* __restrict__ Kg,
                                                bf16* __restrict__ Vg) {
  __shared__ alignas(16) bf16 As[128 * 64];  // 16 KB
  __shared__ alignas(16) bf16 Bs[128 * 64];  // 16 KB
  const int K_ = 2048;
  int tid = threadIdx.x, lane = tid & 63, w = tid >> 6;
  int lr = lane & 15, hi = lane >> 4;
  int wm = (w >> 1) * 64, wn = (w & 1) * 64;
  int m0 = blockIdx.y * 128, n0 = blockIdx.x * 128;
  f32x4 acc[4][4];
#pragma unroll
  for (int im = 0; im < 4; ++im)
#pragma unroll
    for (int in = 0; in < 4; ++in) acc[im][in] = (f32x4){0.f, 0.f, 0.f, 0.f};

  for (int k0 = 0; k0 < K_; k0 += 64) {
    __syncthreads();
#pragma unroll
    for (int i = 0; i < 4; ++i) {
      int c = tid + 256 * i;
      int r = c >> 3, j = c & 7, jg = j ^ (r & 7);
      ASYNC16((char*)As + c * 16, (const char*)(A + (size_t)(m0 + r) * K_ + k0 + jg * 8));
    }
#pragma unroll
    for (int i = 0; i < 4; ++i) {
      int c = tid + 256 * i;
      int r = c >> 3, j = c & 7, jg = j ^ (r & 7);
      ASYNC16((char*)Bs + c * 16, (const char*)(Bt + (size_t)(n0 + r) * K_ + k0 + jg * 8));
    }
    __syncthreads();

#pragma unroll
    for (int ks = 0; ks < 2; ++ks) {
      bf16x8 afr[4], bfr[4];
#pragma unroll
      for (int im = 0; im < 4; ++im) {
        int r = wm + 16 * im + lr;
        afr[im] = *(const bf16x8*)((const char*)As + r * 128 + (((ks * 4 + hi) ^ (r & 7)) * 16));
      }
#pragma unroll
      for (int in = 0; in < 4; ++in) {
        int r = wn + 16 * in + lr;
        bfr[in] = *(const bf16x8*)((const char*)Bs + r * 128 + (((ks * 4 + hi) ^ (r & 7)) * 16));
      }
#pragma unroll
      for (int im = 0; im < 4; ++im)
#pragma unroll
        for (int in = 0; in < 4; ++in)
          acc[im][in] =
              __builtin_amdgcn_mfma_f32_16x16x32_bf16(afr[im], bfr[in], acc[im][in], 0, 0, 0);
    }
  }

  // Epilogue: col c -> which=c>>11; of cc=c&2047: h=cc&15, d=cc>>4.
#pragma unroll
  for (int im = 0; im < 4; ++im) {
    int mrow = m0 + wm + 16 * im + 4 * hi;
#pragma unroll
    for (int in = 0; in < 4; ++in) {
      int c = n0 + wn + 16 * in + lr;
      int which = c >> 11, cc = c & 2047;
      int hh = cc & 15, d = cc >> 4;
      float bv = biasf[c];
#pragma unroll
      for (int j = 0; j < 4; ++j) {
        int m = mrow + j;
        int bb = m >> 11, l = m & 2047;
        int bh = bb * 16 + hh;
        bf16 hv = f2b(acc[im][in][j] + bv);
        if (which == 0)
          Qg[((size_t)bh * 2048 + l) * 128 + d] = hv;
        else if (which == 1)
          Kg[((size_t)bh * 2048 + l) * 128 + d] = hv;
        else
          Vg[((size_t)bh * 128 + d) * 2048 + l] = hv;
      }
    }
  }
}

// ---------------------------------------------------------------------------
// FC2 GEMM: Out(8192,2048) = Y(8192,2048) * Wfc2T(2048,2048)^T, bias+SiLU, fp32 out.
__global__ __launch_bounds__(256) void gemm_fc2(const bf16* __restrict__ A,
                                                const bf16* __restrict__ Bt,
                                                const float* __restrict__ biasf,
                                                float* __restrict__ Out) {
  __shared__ alignas(16) bf16 As[128 * 64];
  __shared__ alignas(16) bf16 Bs[128 * 64];
  const int K_ = 2048;
  int tid = threadIdx.x, lane = tid & 63, w = tid >> 6;
  int lr = lane & 15, hi = lane >> 4;
  int wm = (w >> 1) * 64, wn = (w & 1) * 64;
  int m0 = blockIdx.y * 128, n0 = blockIdx.x * 128;
  f32x4 acc[4][4];
#pragma unroll
  for (int im = 0; im < 4; ++im)
#pragma unroll
    for (int in = 0; in < 4; ++in) acc[im][in] = (f32x4){0.f, 0.f, 0.f, 0.f};

  for (int k0 = 0; k0 < K_; k0 += 64) {
    __syncthreads();
#pragma unroll
    for (int i = 0; i < 4; ++i) {
      int c = tid + 256 * i;
      int r = c >> 3, j = c & 7, jg = j ^ (r & 7);
      ASYNC16((char*)As + c * 16, (const char*)(A + (size_t)(m0 + r) * K_ + k0 + jg * 8));
    }
#pragma unroll
    for (int i = 0; i < 4; ++i) {
      int c = tid + 256 * i;
      int r = c >> 3, j = c & 7, jg = j ^ (r & 7);
      ASYNC16((char*)Bs + c * 16, (const char*)(Bt + (size_t)(n0 + r) * K_ + k0 + jg * 8));
    }
    __syncthreads();
#pragma unroll
    for (int ks = 0; ks < 2; ++ks) {
      bf16x8 afr[4], bfr[4];
#pragma unroll
      for (int im = 0; im < 4; ++im) {
        int r = wm + 16 * im + lr;
        afr[im] = *(const bf16x8*)((const char*)As + r * 128 + (((ks * 4 + hi) ^ (r & 7)) * 16));
      }
#pragma unroll
      for (int in = 0; in < 4; ++in) {
        int r = wn + 16 * in + lr;
        bfr[in] = *(const bf16x8*)((const char*)Bs + r * 128 + (((ks * 4 + hi) ^ (r & 7)) * 16));
      }
#pragma unroll
      for (int im = 0; im < 4; ++im)
#pragma unroll
        for (int in = 0; in < 4; ++in)
          acc[im][in] =
              __builtin_amdgcn_mfma_f32_16x16x32_bf16(afr[im], bfr[in], acc[im][in], 0, 0, 0);
    }
  }

#pragma unroll
  for (int im = 0; im < 4; ++im) {
#pragma unroll
    for (int in = 0; in < 4; ++in) {
      int c = n0 + wn + 16 * in + lr;
      float bv = biasf[c];
#pragma unroll
      for (int j = 0; j < 4; ++j) {
        int m = m0 + wm + 16 * im + 4 * hi + j;
        float z = acc[im][in][j] + bv;
        Out[(size_t)m * 2048 + c] = z / (1.f + __expf(-z));
      }
    }
  }
}

// ---------------------------------------------------------------------------
// Rotary in-place on Q,K head layout. Pair (d, d+64), angle col = d*16+h. fp32 cos/sin.
__global__ void rotary_kernel(bf16* __restrict__ Qg, bf16* __restrict__ Kg,
                              const float* __restrict__ cosp, const float* __restrict__ sinp) {
  int idx = blockIdx.x * 256 + threadIdx.x;  // B*NH*L*64 = 8388608
  int d = idx & 63;
  int l = (idx >> 6) & 2047;
  int bh = idx >> 17;
  int h = bh & 15;
  size_t base = ((size_t)bh * 2048 + l) * 128;
  int ang = l * 1024 + d * 16 + h;
  float c = cosp[ang], s = sinp[ang];
  float q1 = b2f(Qg[base + d]), q2 = b2f(Qg[base + d + 64]);
  Qg[base + d] = f2b(q1 * c + q2 * s);
  Qg[base + d + 64] = f2b(-q1 * s + q2 * c);
  float k1 = b2f(Kg[base + d]), k2 = b2f(Kg[base + d + 64]);
  Kg[base + d] = f2b(k1 * c + k2 * s);
  Kg[base + d + 64] = f2b(-k1 * s + k2 * c);
}

// ---------------------------------------------------------------------------
// Causal flash attention. Round 7: XOR chunk swizzle on Qs/Ks/Vt (confirmed:
// bank conflicts eliminated, 612 -> ~370 us).
__global__ __launch_bounds__(256) void flash_kernel(const bf16* __restrict__ Qg,
                                                    const bf16* __restrict__ Kg,
                                                    const bf16* __restrict__ Vg,
                                                    bf16* __restrict__ Y) {
  __shared__ alignas(16) bf16 Qs[64 * 128];
  __shared__ alignas(16) bf16 Ks[64 * 128];
  __shared__ alignas(16) bf16 Vt[128 * 64];
  __shared__ alignas(16) bf16 Ps[4 * 16 * 72];
  int tid = threadIdx.x, lane = tid & 63, w = tid >> 6;
  int lr = lane & 15, hi = lane >> 4;
  int it = 31 - (int)blockIdx.x;
  int bh = blockIdx.y;
  int b = bh >> 4, h = bh & 15;
  int q0 = it * 64;
  const bf16* Qb = Qg + (size_t)bh * 2048 * 128;
  const bf16* Kb = Kg + (size_t)bh * 2048 * 128;
  const bf16* Vb = Vg + (size_t)bh * 128 * 2048;
  const float NEG = -1.0e30f;

#pragma unroll
  for (int i = 0; i < 4; ++i) {
    int c = tid + 256 * i;
    int r = c >> 4, j = c & 15, jg = j ^ (r & 7);
    ASYNC16((char*)Qs + c * 16, (const char*)(Qb + (size_t)(q0 + r) * 128 + jg * 8));
  }

  f32x4 o[8];
#pragma unroll
  for (int i = 0; i < 8; ++i) o[i] = (f32x4){0.f, 0.f, 0.f, 0.f};
  float m_i[4], l_i[4];
#pragma unroll
  for (int j = 0; j < 4; ++j) { m_i[j] = NEG; l_i[j] = 0.f; }
  const float scale = 0.08838834764831845f;  // 1/sqrt(128)

  for (int jt = 0; jt <= it; ++jt) {
    int k0 = jt * 64;
    __syncthreads();
#pragma unroll
    for (int i = 0; i < 4; ++i) {
      int c = tid + 256 * i;
      int r = c >> 4, j = c & 15, jg = j ^ (r & 7);
      ASYNC16((char*)Ks + c * 16, (const char*)(Kb + (size_t)(k0 + r) * 128 + jg * 8));
    }
#pragma unroll
    for (int i = 0; i < 4; ++i) {
      int c = tid + 256 * i;
      int r = c >> 3, j = c & 7, jg = j ^ (r & 7);
      ASYNC16((char*)Vt + c * 16, (const char*)(Vb + (size_t)r * 2048 + k0 + jg * 8));
    }
    __syncthreads();

    f32x4 sacc[4];
#pragma unroll
    for (int in = 0; in < 4; ++in) sacc[in] = (f32x4){0.f, 0.f, 0.f, 0.f};
#pragma unroll
    for (int ks = 0; ks < 4; ++ks) {
      int ar = 16 * w + lr;
      bf16x8 a = *(const bf16x8*)((const char*)Qs + ar * 256 + (((ks * 4 + hi) ^ (ar & 7)) * 16));
#pragma unroll
      for (int in = 0; in < 4; ++in) {
        int br = 16 * in + lr;
        bf16x8 bb =
            *(const bf16x8*)((const char*)Ks + br * 256 + (((ks * 4 + hi) ^ (br & 7)) * 16));
        sacc[in] = __builtin_amdgcn_mfma_f32_16x16x32_bf16(a, bb, sacc[in], 0, 0, 0);
      }
    }

    bool diag = (jt == it);
#pragma unroll
    for (int j = 0; j < 4; ++j) {
      float mx = NEG;
#pragma unroll
      for (int in = 0; in < 4; ++in) {
        float s = sacc[in][j] * scale;
        if (diag) {
          int qg = 16 * w + 4 * hi + j;
          int kg = 16 * in + lr;
          if (kg > qg) s = NEG;
        }
        sacc[in][j] = s;
        mx = fmaxf(mx, s);
      }
#pragma unroll
      for (int off = 1; off < 16; off <<= 1) mx = fmaxf(mx, __shfl_xor(mx, off));
      float mnew = fmaxf(m_i[j], mx);
      float alpha = __expf(m_i[j] - mnew);
      float rs = 0.f;
#pragma unroll
      for (int in = 0; in < 4; ++in) {
        float p = __expf(sacc[in][j] - mnew);
        sacc[in][j] = p;
        rs += p;
      }
#pragma unroll
      for (int off = 1; off < 16; off <<= 1) rs += __shfl_xor(rs, off);
      l_i[j] = alpha * l_i[j] + rs;
      m_i[j] = mnew;
#pragma unroll
      for (int inp = 0; inp < 8; ++inp) o[inp][j] *= alpha;
    }

#pragma unroll
    for (int j = 0; j < 4; ++j)
#pragma unroll
      for (int in = 0; in < 4; ++in)
        Ps[w * 1152 + (4 * hi + j) * 72 + 16 * in + lr] = f2b(sacc[in][j]);
    __syncthreads();

#pragma unroll
    for (int ko = 0; ko < 2; ++ko) {
      bf16x8 a = *(const bf16x8*)((const char*)Ps + (w * 1152 + lr * 72 + ko * 32 + hi * 8) * 2);
#pragma unroll
      for (int inp = 0; inp < 8; ++inp) {
        int br = 16 * inp + lr;
        bf16x8 bb =
            *(const bf16x8*)((const char*)Vt + br * 128 + (((ko * 4 + hi) ^ (br & 7)) * 16));
        o[inp] = __builtin_amdgcn_mfma_f32_16x16x32_bf16(a, bb, o[inp], 0, 0, 0);
      }
    }
  }

#pragma unroll
  for (int j = 0; j < 4; ++j) {
    int qg = q0 + 16 * w + 4 * hi + j;
    float inv = 1.f / l_i[j];
    size_t rowb = ((size_t)(b * 2048 + qg)) * 2048 + h * 128;
#pragma unroll
    for (int inp = 0; inp < 8; ++inp) {
      int dd = 16 * inp + lr;
      Y[rowb + dd] = f2b(o[inp][j] * inv);
    }
  }
}

// ---------------------------------------------------------------------------
extern "C" void kernel_launch(void* const* d_in, const int* in_sizes, int n_in,
                              void* d_out, int out_size, void* d_ws, size_t ws_size,
                              hipStream_t stream) {
  const float* x    = (const float*)d_in[0];  // 8192 x 2048
  const float* Wqkv = (const float*)d_in[1];  // 2048 x 6144
  const float* bqkv = (const float*)d_in[2];  // 6144
  const float* Wfc2 = (const float*)d_in[3];  // 2048 x 2048
  const float* bfc2 = (const float*)d_in[4];  // 2048
  const float* cosp = (const float*)d_in[5];  // 2048 x 1024
  const float* sinp = (const float*)d_in[6];  // 2048 x 1024
  float* out = (float*)d_out;

  // Workspace (bf16 elems), exactly 67,108,864 = 128 MB:
  //   [0, 16.78M):      Yg (flash out). WqkvT [0,12.58M) aliased pre-flash.
  //   [16.78M, 33.55M): Qg. Wfc2T [+0,+4.19M) aliased post-flash.
  //   [33.55M, 50.33M): Kg.
  //   [50.33M, 67.11M): Vg [bh][128][l].
  // x_bf16 (16.78M elems = 33.5 MB) parked in d_out (67 MB fp32, dead until fc2).
  bf16* ws = (bf16*)d_ws;
  bf16* Yg    = ws;
  bf16* WqkvT = ws;
  bf16* Qg    = ws + 16777216;
  bf16* Wfc2T = ws + 16777216;
  bf16* Kg    = ws + 33554432;
  bf16* Vg    = ws + 50331648;
  bf16* xb    = (bf16*)d_out;

  conv_bf16<<<8192, 256, 0, stream>>>(x, xb);
  transpose_conv<<<dim3(192, 64), dim3(32, 8), 0, stream>>>(Wqkv, WqkvT, 2048, 6144);
  gemm_qkv<<<dim3(48, 64), 256, 0, stream>>>(xb, WqkvT, bqkv, Qg, Kg, Vg);
  rotary_kernel<<<32768, 256, 0, stream>>>(Qg, Kg, cosp, sinp);
  flash_kernel<<<dim3(32, 64), 256, 0, stream>>>(Qg, Kg, Vg, Yg);
  transpose_conv<<<dim3(64, 64), dim3(32, 8), 0, stream>>>(Wfc2, Wfc2T, 2048, 2048);
  gemm_fc2<<<dim3(16, 64), 256, 0, stream>>>(Yg, Wfc2T, bfc2, out);
}

// Round 5
// 862.897 us; speedup vs baseline: 1.5629x; 1.1961x over previous
//
#include <hip/hip_runtime.h>
#include <hip/hip_bf16.h>
#include <cstdint>
#include <cstddef>

// B=4, L=2048, H=2048, NH=16, HD=128. Inputs/outputs fp32.
// Round 7: XOR chunk swizzle on flash Qs/Ks/Vt — flash 612 -> ~370 us. CONFIRMED.
// Round 9: bf16-pre-convert x (parked in d_out), gemm_qkv ASYNC16 both operands.
//          527 -> 426 us. Partial: epilogue scatter remained (WRITE_SIZE 320 MB
//          = 3.2x amplification; 16 lanes write 16 heads 512 KB apart).
// Round 10: WqkvT rows PERMUTED so GEMM col c' = which*2048 + h*128 + d (d-fast).
//          Q/K epilogue stores now d-contiguous (32B runs/instruction). V-blocks
//          own a full [128d][128l] panel: acc restaged through 32 KB LDS (XOR'd
//          l-chunks, <=2-way) then 16B coalesced stores. Bias remapped via inverse
//          perm. Rotary/flash untouched. Workspace exactly 128 MB.
// Round 11: resubmit of round 10 unchanged (container infra failure, no counters).

typedef __attribute__((ext_vector_type(4))) float f32x4;
typedef __attribute__((ext_vector_type(8))) short bf16x8;
typedef __hip_bfloat16 bf16;

#define ASYNC16(lds, g)                                                                  \
  __builtin_amdgcn_global_load_lds((const __attribute__((address_space(1))) void*)(g),   \
                                   (__attribute__((address_space(3))) void*)(lds), 16, 0, 0)

__device__ __forceinline__ float b2f(bf16 v) { return __bfloat162float(v); }
__device__ __forceinline__ bf16 f2b(float v) { return __float2bfloat16(v); }
__device__ __forceinline__ short f2bs(float f) {
  bf16 h = __float2bfloat16(f);
  return __builtin_bit_cast(short, h);
}
__device__ __forceinline__ bf16x8 pack8(f32x4 a, f32x4 b) {
  bf16x8 r;
#pragma unroll
  for (int t = 0; t < 4; ++t) r[t] = f2bs(a[t]);
#pragma unroll
  for (int t = 0; t < 4; ++t) r[4 + t] = f2bs(b[t]);
  return r;
}

// ---------------------------------------------------------------------------
// Elementwise fp32 -> bf16, 8 elems/thread, fully coalesced.
__global__ void conv_bf16(const float* __restrict__ src, bf16* __restrict__ dst) {
  size_t i = ((size_t)blockIdx.x * 256 + threadIdx.x) * 8;
  f32x4 a0 = *(const f32x4*)(src + i);
  f32x4 a1 = *(const f32x4*)(src + i + 4);
  *(bf16x8*)(dst + i) = pack8(a0, a1);
}

// ---------------------------------------------------------------------------
// Transpose+convert fp32 (R x C) -> bf16 (C x R). perm=1: qkv column remap
// col = which*2048 + d*16 + h  ->  which*2048 + h*128 + d  (dst-row permute).
__global__ void transpose_conv(const float* __restrict__ src, bf16* __restrict__ dst,
                               int R, int C, int perm) {
  __shared__ float tile[32][33];
  int bx = blockIdx.x * 32, by = blockIdx.y * 32;
  int tx = threadIdx.x, ty = threadIdx.y;
  for (int i = ty; i < 32; i += 8) tile[i][tx] = src[(size_t)(by + i) * C + bx + tx];
  __syncthreads();
  for (int i = ty; i < 32; i += 8) {
    int c = bx + i;
    if (perm) {
      int cc = c & 2047;
      c = (c & ~2047) | (((cc & 15) << 7) | (cc >> 4));
    }
    dst[(size_t)c * R + by + tx] = f2b(tile[tx][i]);
  }
}

// ---------------------------------------------------------------------------
// QKV GEMM: C(8192,6144) = xb(8192,2048) * WqkvT(6144,2048)^T. 128x128, BK=64.
// Columns permuted (d-fast). Per n-tile: one (which,h), full d in [0,128).
__global__ __launch_bounds__(256) void gemm_qkv(const bf16* __restrict__ A,
                                                const bf16* __restrict__ Bt,
                                                const float* __restrict__ biasf,
                                                bf16* __restrict__ Qg, bf16* __restrict__ Kg,
                                                bf16* __restrict__ Vg) {
  __shared__ alignas(16) bf16 smem[2 * 128 * 64];  // As | Bs; reused as [128][128] for V restage
  bf16* As = smem;
  bf16* Bs = smem + 128 * 64;
  const int K_ = 2048;
  int tid = threadIdx.x, lane = tid & 63, w = tid >> 6;
  int lr = lane & 15, hi = lane >> 4;
  int wm = (w >> 1) * 64, wn = (w & 1) * 64;
  int m0 = blockIdx.y * 128, n0 = blockIdx.x * 128;
  f32x4 acc[4][4];
#pragma unroll
  for (int im = 0; im < 4; ++im)
#pragma unroll
    for (int in = 0; in < 4; ++in) acc[im][in] = (f32x4){0.f, 0.f, 0.f, 0.f};

  for (int k0 = 0; k0 < K_; k0 += 64) {
    __syncthreads();
#pragma unroll
    for (int i = 0; i < 4; ++i) {
      int c = tid + 256 * i;
      int r = c >> 3, j = c & 7, jg = j ^ (r & 7);
      ASYNC16((char*)As + c * 16, (const char*)(A + (size_t)(m0 + r) * K_ + k0 + jg * 8));
    }
#pragma unroll
    for (int i = 0; i < 4; ++i) {
      int c = tid + 256 * i;
      int r = c >> 3, j = c & 7, jg = j ^ (r & 7);
      ASYNC16((char*)Bs + c * 16, (const char*)(Bt + (size_t)(n0 + r) * K_ + k0 + jg * 8));
    }
    __syncthreads();

#pragma unroll
    for (int ks = 0; ks < 2; ++ks) {
      bf16x8 afr[4], bfr[4];
#pragma unroll
      for (int im = 0; im < 4; ++im) {
        int r = wm + 16 * im + lr;
        afr[im] = *(const bf16x8*)((const char*)As + r * 128 + (((ks * 4 + hi) ^ (r & 7)) * 16));
      }
#pragma unroll
      for (int in = 0; in < 4; ++in) {
        int r = wn + 16 * in + lr;
        bfr[in] = *(const bf16x8*)((const char*)Bs + r * 128 + (((ks * 4 + hi) ^ (r & 7)) * 16));
      }
#pragma unroll
      for (int im = 0; im < 4; ++im)
#pragma unroll
        for (int in = 0; in < 4; ++in)
          acc[im][in] =
              __builtin_amdgcn_mfma_f32_16x16x32_bf16(afr[im], bfr[in], acc[im][in], 0, 0, 0);
    }
  }

  // Epilogue. Block-uniform: which, h. d = wn + 16*in + lr (full [0,128) per tile).
  int which = n0 >> 11;
  int h = (n0 >> 7) & 15;
  int bq = m0 >> 11;
  int l_base = m0 & 2047;
  int bh = bq * 16 + h;
  float bv[4];
#pragma unroll
  for (int in = 0; in < 4; ++in)
    bv[in] = biasf[(which << 11) + ((wn + 16 * in + lr) << 4) + h];

  if (which < 2) {
    bf16* __restrict__ G = (which == 0) ? Qg : Kg;
#pragma unroll
    for (int im = 0; im < 4; ++im) {
#pragma unroll
      for (int in = 0; in < 4; ++in) {
        int d = wn + 16 * in + lr;
#pragma unroll
        for (int j = 0; j < 4; ++j) {
          int l = l_base + wm + 16 * im + 4 * hi + j;
          G[((size_t)bh * 2048 + l) * 128 + d] = f2b(acc[im][in][j] + bv[in]);
        }
      }
    }
  } else {
    // V: restage [128 d][128 l] through LDS (XOR'd 8-elem l-chunks), 16B stores.
    __syncthreads();
#pragma unroll
    for (int im = 0; im < 4; ++im)
#pragma unroll
      for (int in = 0; in < 4; ++in) {
        int d = wn + 16 * in + lr;
#pragma unroll
        for (int j = 0; j < 4; ++j) {
          int l = wm + 16 * im + 4 * hi + j;
          int slot = (l >> 3) ^ (d & 15);
          smem[d * 128 + slot * 8 + (l & 7)] = f2b(acc[im][in][j] + bv[in]);
        }
      }
    __syncthreads();
#pragma unroll
    for (int s = 0; s < 8; ++s) {
      int d = (tid >> 4) + 16 * s;
      int lc = tid & 15;
      int slot = lc ^ (d & 15);
      bf16x8 v = *(const bf16x8*)(smem + d * 128 + slot * 8);
      *(bf16x8*)(Vg + ((size_t)bh * 128 + d) * 2048 + l_base + lc * 8) = v;
    }
  }
}

// ---------------------------------------------------------------------------
// FC2 GEMM: Out(8192,2048) = Y(8192,2048) * Wfc2T(2048,2048)^T, bias+SiLU, fp32 out.
__global__ __launch_bounds__(256) void gemm_fc2(const bf16* __restrict__ A,
                                                const bf16* __restrict__ Bt,
                                                const float* __restrict__ biasf,
                                                float* __restrict__ Out) {
  __shared__ alignas(16) bf16 As[128 * 64];
  __shared__ alignas(16) bf16 Bs[128 * 64];
  const int K_ = 2048;
  int tid = threadIdx.x, lane = tid & 63, w = tid >> 6;
  int lr = lane & 15, hi = lane >> 4;
  int wm = (w >> 1) * 64, wn = (w & 1) * 64;
  int m0 = blockIdx.y * 128, n0 = blockIdx.x * 128;
  f32x4 acc[4][4];
#pragma unroll
  for (int im = 0; im < 4; ++im)
#pragma unroll
    for (int in = 0; in < 4; ++in) acc[im][in] = (f32x4){0.f, 0.f, 0.f, 0.f};

  for (int k0 = 0; k0 < K_; k0 += 64) {
    __syncthreads();
#pragma unroll
    for (int i = 0; i < 4; ++i) {
      int c = tid + 256 * i;
      int r = c >> 3, j = c & 7, jg = j ^ (r & 7);
      ASYNC16((char*)As + c * 16, (const char*)(A + (size_t)(m0 + r) * K_ + k0 + jg * 8));
    }
#pragma unroll
    for (int i = 0; i < 4; ++i) {
      int c = tid + 256 * i;
      int r = c >> 3, j = c & 7, jg = j ^ (r & 7);
      ASYNC16((char*)Bs + c * 16, (const char*)(Bt + (size_t)(n0 + r) * K_ + k0 + jg * 8));
    }
    __syncthreads();
#pragma unroll
    for (int ks = 0; ks < 2; ++ks) {
      bf16x8 afr[4], bfr[4];
#pragma unroll
      for (int im = 0; im < 4; ++im) {
        int r = wm + 16 * im + lr;
        afr[im] = *(const bf16x8*)((const char*)As + r * 128 + (((ks * 4 + hi) ^ (r & 7)) * 16));
      }
#pragma unroll
      for (int in = 0; in < 4; ++in) {
        int r = wn + 16 * in + lr;
        bfr[in] = *(const bf16x8*)((const char*)Bs + r * 128 + (((ks * 4 + hi) ^ (r & 7)) * 16));
      }
#pragma unroll
      for (int im = 0; im < 4; ++im)
#pragma unroll
        for (int in = 0; in < 4; ++in)
          acc[im][in] =
              __builtin_amdgcn_mfma_f32_16x16x32_bf16(afr[im], bfr[in], acc[im][in], 0, 0, 0);
    }
  }

#pragma unroll
  for (int im = 0; im < 4; ++im) {
#pragma unroll
    for (int in = 0; in < 4; ++in) {
      int c = n0 + wn + 16 * in + lr;
      float bv = biasf[c];
#pragma unroll
      for (int j = 0; j < 4; ++j) {
        int m = m0 + wm + 16 * im + 4 * hi + j;
        float z = acc[im][in][j] + bv;
        Out[(size_t)m * 2048 + c] = z / (1.f + __expf(-z));
      }
    }
  }
}

// ---------------------------------------------------------------------------
// Rotary in-place on Q,K head layout. Pair (d, d+64), angle col = d*16+h. fp32 cos/sin.
__global__ void rotary_kernel(bf16* __restrict__ Qg, bf16* __restrict__ Kg,
                              const float* __restrict__ cosp, const float* __restrict__ sinp) {
  int idx = blockIdx.x * 256 + threadIdx.x;  // B*NH*L*64 = 8388608
  int d = idx & 63;
  int l = (idx >> 6) & 2047;
  int bh = idx >> 17;
  int h = bh & 15;
  size_t base = ((size_t)bh * 2048 + l) * 128;
  int ang = l * 1024 + d * 16 + h;
  float c = cosp[ang], s = sinp[ang];
  float q1 = b2f(Qg[base + d]), q2 = b2f(Qg[base + d + 64]);
  Qg[base + d] = f2b(q1 * c + q2 * s);
  Qg[base + d + 64] = f2b(-q1 * s + q2 * c);
  float k1 = b2f(Kg[base + d]), k2 = b2f(Kg[base + d + 64]);
  Kg[base + d] = f2b(k1 * c + k2 * s);
  Kg[base + d + 64] = f2b(-k1 * s + k2 * c);
}

// ---------------------------------------------------------------------------
// Causal flash attention. Round 7: XOR chunk swizzle on Qs/Ks/Vt (confirmed:
// bank conflicts eliminated, 612 -> ~370 us).
__global__ __launch_bounds__(256) void flash_kernel(const bf16* __restrict__ Qg,
                                                    const bf16* __restrict__ Kg,
                                                    const bf16* __restrict__ Vg,
                                                    bf16* __restrict__ Y) {
  __shared__ alignas(16) bf16 Qs[64 * 128];
  __shared__ alignas(16) bf16 Ks[64 * 128];
  __shared__ alignas(16) bf16 Vt[128 * 64];
  __shared__ alignas(16) bf16 Ps[4 * 16 * 72];
  int tid = threadIdx.x, lane = tid & 63, w = tid >> 6;
  int lr = lane & 15, hi = lane >> 4;
  int it = 31 - (int)blockIdx.x;
  int bh = blockIdx.y;
  int b = bh >> 4, h = bh & 15;
  int q0 = it * 64;
  const bf16* Qb = Qg + (size_t)bh * 2048 * 128;
  const bf16* Kb = Kg + (size_t)bh * 2048 * 128;
  const bf16* Vb = Vg + (size_t)bh * 128 * 2048;
  const float NEG = -1.0e30f;

#pragma unroll
  for (int i = 0; i < 4; ++i) {
    int c = tid + 256 * i;
    int r = c >> 4, j = c & 15, jg = j ^ (r & 7);
    ASYNC16((char*)Qs + c * 16, (const char*)(Qb + (size_t)(q0 + r) * 128 + jg * 8));
  }

  f32x4 o[8];
#pragma unroll
  for (int i = 0; i < 8; ++i) o[i] = (f32x4){0.f, 0.f, 0.f, 0.f};
  float m_i[4], l_i[4];
#pragma unroll
  for (int j = 0; j < 4; ++j) { m_i[j] = NEG; l_i[j] = 0.f; }
  const float scale = 0.08838834764831845f;  // 1/sqrt(128)

  for (int jt = 0; jt <= it; ++jt) {
    int k0 = jt * 64;
    __syncthreads();
#pragma unroll
    for (int i = 0; i < 4; ++i) {
      int c = tid + 256 * i;
      int r = c >> 4, j = c & 15, jg = j ^ (r & 7);
      ASYNC16((char*)Ks + c * 16, (const char*)(Kb + (size_t)(k0 + r) * 128 + jg * 8));
    }
#pragma unroll
    for (int i = 0; i < 4; ++i) {
      int c = tid + 256 * i;
      int r = c >> 3, j = c & 7, jg = j ^ (r & 7);
      ASYNC16((char*)Vt + c * 16, (const char*)(Vb + (size_t)r * 2048 + k0 + jg * 8));
    }
    __syncthreads();

    f32x4 sacc[4];
#pragma unroll
    for (int in = 0; in < 4; ++in) sacc[in] = (f32x4){0.f, 0.f, 0.f, 0.f};
#pragma unroll
    for (int ks = 0; ks < 4; ++ks) {
      int ar = 16 * w + lr;
      bf16x8 a = *(const bf16x8*)((const char*)Qs + ar * 256 + (((ks * 4 + hi) ^ (ar & 7)) * 16));
#pragma unroll
      for (int in = 0; in < 4; ++in) {
        int br = 16 * in + lr;
        bf16x8 bb =
            *(const bf16x8*)((const char*)Ks + br * 256 + (((ks * 4 + hi) ^ (br & 7)) * 16));
        sacc[in] = __builtin_amdgcn_mfma_f32_16x16x32_bf16(a, bb, sacc[in], 0, 0, 0);
      }
    }

    bool diag = (jt == it);
#pragma unroll
    for (int j = 0; j < 4; ++j) {
      float mx = NEG;
#pragma unroll
      for (int in = 0; in < 4; ++in) {
        float s = sacc[in][j] * scale;
        if (diag) {
          int qg = 16 * w + 4 * hi + j;
          int kg = 16 * in + lr;
          if (kg > qg) s = NEG;
        }
        sacc[in][j] = s;
        mx = fmaxf(mx, s);
      }
#pragma unroll
      for (int off = 1; off < 16; off <<= 1) mx = fmaxf(mx, __shfl_xor(mx, off));
      float mnew = fmaxf(m_i[j], mx);
      float alpha = __expf(m_i[j] - mnew);
      float rs = 0.f;
#pragma unroll
      for (int in = 0; in < 4; ++in) {
        float p = __expf(sacc[in][j] - mnew);
        sacc[in][j] = p;
        rs += p;
      }
#pragma unroll
      for (int off = 1; off < 16; off <<= 1) rs += __shfl_xor(rs, off);
      l_i[j] = alpha * l_i[j] + rs;
      m_i[j] = mnew;
#pragma unroll
      for (int inp = 0; inp < 8; ++inp) o[inp][j] *= alpha;
    }

#pragma unroll
    for (int j = 0; j < 4; ++j)
#pragma unroll
      for (int in = 0; in < 4; ++in)
        Ps[w * 1152 + (4 * hi + j) * 72 + 16 * in + lr] = f2b(sacc[in][j]);
    __syncthreads();

#pragma unroll
    for (int ko = 0; ko < 2; ++ko) {
      bf16x8 a = *(const bf16x8*)((const char*)Ps + (w * 1152 + lr * 72 + ko * 32 + hi * 8) * 2);
#pragma unroll
      for (int inp = 0; inp < 8; ++inp) {
        int br = 16 * inp + lr;
        bf16x8 bb =
            *(const bf16x8*)((const char*)Vt + br * 128 + (((ko * 4 + hi) ^ (br & 7)) * 16));
        o[inp] = __builtin_amdgcn_mfma_f32_16x16x32_bf16(a, bb, o[inp], 0, 0, 0);
      }
    }
  }

#pragma unroll
  for (int j = 0; j < 4; ++j) {
    int qg = q0 + 16 * w + 4 * hi + j;
    float inv = 1.f / l_i[j];
    size_t rowb = ((size_t)(b * 2048 + qg)) * 2048 + h * 128;
#pragma unroll
    for (int inp = 0; inp < 8; ++inp) {
      int dd = 16 * inp + lr;
      Y[rowb + dd] = f2b(o[inp][j] * inv);
    }
  }
}

// ---------------------------------------------------------------------------
extern "C" void kernel_launch(void* const* d_in, const int* in_sizes, int n_in,
                              void* d_out, int out_size, void* d_ws, size_t ws_size,
                              hipStream_t stream) {
  const float* x    = (const float*)d_in[0];  // 8192 x 2048
  const float* Wqkv = (const float*)d_in[1];  // 2048 x 6144
  const float* bqkv = (const float*)d_in[2];  // 6144
  const float* Wfc2 = (const float*)d_in[3];  // 2048 x 2048
  const float* bfc2 = (const float*)d_in[4];  // 2048
  const float* cosp = (const float*)d_in[5];  // 2048 x 1024
  const float* sinp = (const float*)d_in[6];  // 2048 x 1024
  float* out = (float*)d_out;

  // Workspace (bf16 elems), exactly 67,108,864 = 128 MB:
  //   [0, 16.78M):      Yg (flash out). WqkvT [0,12.58M) aliased pre-flash.
  //   [16.78M, 33.55M): Qg. Wfc2T [+0,+4.19M) aliased post-flash.
  //   [33.55M, 50.33M): Kg.
  //   [50.33M, 67.11M): Vg [bh][128][l].
  // x_bf16 (16.78M elems = 33.5 MB) parked in d_out (67 MB fp32, dead until fc2).
  bf16* ws = (bf16*)d_ws;
  bf16* Yg    = ws;
  bf16* WqkvT = ws;
  bf16* Qg    = ws + 16777216;
  bf16* Wfc2T = ws + 16777216;
  bf16* Kg    = ws + 33554432;
  bf16* Vg    = ws + 50331648;
  bf16* xb    = (bf16*)d_out;

  conv_bf16<<<8192, 256, 0, stream>>>(x, xb);
  transpose_conv<<<dim3(192, 64), dim3(32, 8), 0, stream>>>(Wqkv, WqkvT, 2048, 6144, 1);
  gemm_qkv<<<dim3(48, 64), 256, 0, stream>>>(xb, WqkvT, bqkv, Qg, Kg, Vg);
  rotary_kernel<<<32768, 256, 0, stream>>>(Qg, Kg, cosp, sinp);
  flash_kernel<<<dim3(32, 64), 256, 0, stream>>>(Qg, Kg, Vg, Yg);
  transpose_conv<<<dim3(64, 64), dim3(32, 8), 0, stream>>>(Wfc2, Wfc2T, 2048, 2048, 0);
  gemm_fc2<<<dim3(16, 64), 256, 0, stream>>>(Yg, Wfc2T, bfc2, out);
}

// Round 6
// 860.403 us; speedup vs baseline: 1.5674x; 1.0029x over previous
//
#include <hip/hip_runtime.h>
#include <hip/hip_bf16.h>
#include <cstdint>
#include <cstddef>

// B=4, L=2048, H=2048, NH=16, HD=128. Inputs/outputs fp32.
// Round 7:  XOR chunk swizzle on flash Qs/Ks/Vt — flash 612 -> ~370 us. CONFIRMED.
// Round 9:  bf16-pre-convert x; gemm_qkv ASYNC16 both operands. 527 -> 426 us.
// Round 10: WqkvT d-fast column permute + LDS-restaged V epilogue. WRITE 320->~105MB,
//           gemm_qkv 426 -> <360 us, total 1032 -> 863. CONFIRMED.
// Round 12: flash was 362 us, Occupancy 11% (LDS 57KB -> 2 blocks/CU), MfmaUtil 8%,
//           serial per-iter chain with vmcnt(0) drain. Now: (a) Q held in REGISTERS
//           (wave reads only its own 16 rows; Qs buffer deleted -> LDS 41KB -> 3
//           blocks/CU); (b) T14 async-STAGE: K/V global loads for jt+1 issued into
//           regs during jt's compute, ds_write at jt+1 top (latency hidden; no
//           ASYNC16 drain); (c) post-Ps barrier replaced by wave-local lgkmcnt(0)
//           (Ps is wave-private) -> 2 barriers/iter. Workspace exactly 128 MB.

typedef __attribute__((ext_vector_type(4))) float f32x4;
typedef __attribute__((ext_vector_type(8))) short bf16x8;
typedef __hip_bfloat16 bf16;

#define ASYNC16(lds, g)                                                                  \
  __builtin_amdgcn_global_load_lds((const __attribute__((address_space(1))) void*)(g),   \
                                   (__attribute__((address_space(3))) void*)(lds), 16, 0, 0)

__device__ __forceinline__ float b2f(bf16 v) { return __bfloat162float(v); }
__device__ __forceinline__ bf16 f2b(float v) { return __float2bfloat16(v); }
__device__ __forceinline__ short f2bs(float f) {
  bf16 h = __float2bfloat16(f);
  return __builtin_bit_cast(short, h);
}
__device__ __forceinline__ bf16x8 pack8(f32x4 a, f32x4 b) {
  bf16x8 r;
#pragma unroll
  for (int t = 0; t < 4; ++t) r[t] = f2bs(a[t]);
#pragma unroll
  for (int t = 0; t < 4; ++t) r[4 + t] = f2bs(b[t]);
  return r;
}

// ---------------------------------------------------------------------------
// Elementwise fp32 -> bf16, 8 elems/thread, fully coalesced.
__global__ void conv_bf16(const float* __restrict__ src, bf16* __restrict__ dst) {
  size_t i = ((size_t)blockIdx.x * 256 + threadIdx.x) * 8;
  f32x4 a0 = *(const f32x4*)(src + i);
  f32x4 a1 = *(const f32x4*)(src + i + 4);
  *(bf16x8*)(dst + i) = pack8(a0, a1);
}

// ---------------------------------------------------------------------------
// Transpose+convert fp32 (R x C) -> bf16 (C x R). perm=1: qkv column remap
// col = which*2048 + d*16 + h  ->  which*2048 + h*128 + d  (dst-row permute).
__global__ void transpose_conv(const float* __restrict__ src, bf16* __restrict__ dst,
                               int R, int C, int perm) {
  __shared__ float tile[32][33];
  int bx = blockIdx.x * 32, by = blockIdx.y * 32;
  int tx = threadIdx.x, ty = threadIdx.y;
  for (int i = ty; i < 32; i += 8) tile[i][tx] = src[(size_t)(by + i) * C + bx + tx];
  __syncthreads();
  for (int i = ty; i < 32; i += 8) {
    int c = bx + i;
    if (perm) {
      int cc = c & 2047;
      c = (c & ~2047) | (((cc & 15) << 7) | (cc >> 4));
    }
    dst[(size_t)c * R + by + tx] = f2b(tile[tx][i]);
  }
}

// ---------------------------------------------------------------------------
// QKV GEMM: C(8192,6144) = xb(8192,2048) * WqkvT(6144,2048)^T. 128x128, BK=64.
// Columns permuted (d-fast). Per n-tile: one (which,h), full d in [0,128).
__global__ __launch_bounds__(256) void gemm_qkv(const bf16* __restrict__ A,
                                                const bf16* __restrict__ Bt,
                                                const float* __restrict__ biasf,
                                                bf16* __restrict__ Qg, bf16* __restrict__ Kg,
                                                bf16* __restrict__ Vg) {
  __shared__ alignas(16) bf16 smem[2 * 128 * 64];  // As | Bs; reused as [128][128] for V restage
  bf16* As = smem;
  bf16* Bs = smem + 128 * 64;
  const int K_ = 2048;
  int tid = threadIdx.x, lane = tid & 63, w = tid >> 6;
  int lr = lane & 15, hi = lane >> 4;
  int wm = (w >> 1) * 64, wn = (w & 1) * 64;
  int m0 = blockIdx.y * 128, n0 = blockIdx.x * 128;
  f32x4 acc[4][4];
#pragma unroll
  for (int im = 0; im < 4; ++im)
#pragma unroll
    for (int in = 0; in < 4; ++in) acc[im][in] = (f32x4){0.f, 0.f, 0.f, 0.f};

  for (int k0 = 0; k0 < K_; k0 += 64) {
    __syncthreads();
#pragma unroll
    for (int i = 0; i < 4; ++i) {
      int c = tid + 256 * i;
      int r = c >> 3, j = c & 7, jg = j ^ (r & 7);
      ASYNC16((char*)As + c * 16, (const char*)(A + (size_t)(m0 + r) * K_ + k0 + jg * 8));
    }
#pragma unroll
    for (int i = 0; i < 4; ++i) {
      int c = tid + 256 * i;
      int r = c >> 3, j = c & 7, jg = j ^ (r & 7);
      ASYNC16((char*)Bs + c * 16, (const char*)(Bt + (size_t)(n0 + r) * K_ + k0 + jg * 8));
    }
    __syncthreads();

#pragma unroll
    for (int ks = 0; ks < 2; ++ks) {
      bf16x8 afr[4], bfr[4];
#pragma unroll
      for (int im = 0; im < 4; ++im) {
        int r = wm + 16 * im + lr;
        afr[im] = *(const bf16x8*)((const char*)As + r * 128 + (((ks * 4 + hi) ^ (r & 7)) * 16));
      }
#pragma unroll
      for (int in = 0; in < 4; ++in) {
        int r = wn + 16 * in + lr;
        bfr[in] = *(const bf16x8*)((const char*)Bs + r * 128 + (((ks * 4 + hi) ^ (r & 7)) * 16));
      }
#pragma unroll
      for (int im = 0; im < 4; ++im)
#pragma unroll
        for (int in = 0; in < 4; ++in)
          acc[im][in] =
              __builtin_amdgcn_mfma_f32_16x16x32_bf16(afr[im], bfr[in], acc[im][in], 0, 0, 0);
    }
  }

  // Epilogue. Block-uniform: which, h. d = wn + 16*in + lr (full [0,128) per tile).
  int which = n0 >> 11;
  int h = (n0 >> 7) & 15;
  int bq = m0 >> 11;
  int l_base = m0 & 2047;
  int bh = bq * 16 + h;
  float bv[4];
#pragma unroll
  for (int in = 0; in < 4; ++in)
    bv[in] = biasf[(which << 11) + ((wn + 16 * in + lr) << 4) + h];

  if (which < 2) {
    bf16* __restrict__ G = (which == 0) ? Qg : Kg;
#pragma unroll
    for (int im = 0; im < 4; ++im) {
#pragma unroll
      for (int in = 0; in < 4; ++in) {
        int d = wn + 16 * in + lr;
#pragma unroll
        for (int j = 0; j < 4; ++j) {
          int l = l_base + wm + 16 * im + 4 * hi + j;
          G[((size_t)bh * 2048 + l) * 128 + d] = f2b(acc[im][in][j] + bv[in]);
        }
      }
    }
  } else {
    // V: restage [128 d][128 l] through LDS (XOR'd 8-elem l-chunks), 16B stores.
    __syncthreads();
#pragma unroll
    for (int im = 0; im < 4; ++im)
#pragma unroll
      for (int in = 0; in < 4; ++in) {
        int d = wn + 16 * in + lr;
#pragma unroll
        for (int j = 0; j < 4; ++j) {
          int l = wm + 16 * im + 4 * hi + j;
          int slot = (l >> 3) ^ (d & 15);
          smem[d * 128 + slot * 8 + (l & 7)] = f2b(acc[im][in][j] + bv[in]);
        }
      }
    __syncthreads();
#pragma unroll
    for (int s = 0; s < 8; ++s) {
      int d = (tid >> 4) + 16 * s;
      int lc = tid & 15;
      int slot = lc ^ (d & 15);
      bf16x8 v = *(const bf16x8*)(smem + d * 128 + slot * 8);
      *(bf16x8*)(Vg + ((size_t)bh * 128 + d) * 2048 + l_base + lc * 8) = v;
    }
  }
}

// ---------------------------------------------------------------------------
// FC2 GEMM: Out(8192,2048) = Y(8192,2048) * Wfc2T(2048,2048)^T, bias+SiLU, fp32 out.
__global__ __launch_bounds__(256) void gemm_fc2(const bf16* __restrict__ A,
                                                const bf16* __restrict__ Bt,
                                                const float* __restrict__ biasf,
                                                float* __restrict__ Out) {
  __shared__ alignas(16) bf16 As[128 * 64];
  __shared__ alignas(16) bf16 Bs[128 * 64];
  const int K_ = 2048;
  int tid = threadIdx.x, lane = tid & 63, w = tid >> 6;
  int lr = lane & 15, hi = lane >> 4;
  int wm = (w >> 1) * 64, wn = (w & 1) * 64;
  int m0 = blockIdx.y * 128, n0 = blockIdx.x * 128;
  f32x4 acc[4][4];
#pragma unroll
  for (int im = 0; im < 4; ++im)
#pragma unroll
    for (int in = 0; in < 4; ++in) acc[im][in] = (f32x4){0.f, 0.f, 0.f, 0.f};

  for (int k0 = 0; k0 < K_; k0 += 64) {
    __syncthreads();
#pragma unroll
    for (int i = 0; i < 4; ++i) {
      int c = tid + 256 * i;
      int r = c >> 3, j = c & 7, jg = j ^ (r & 7);
      ASYNC16((char*)As + c * 16, (const char*)(A + (size_t)(m0 + r) * K_ + k0 + jg * 8));
    }
#pragma unroll
    for (int i = 0; i < 4; ++i) {
      int c = tid + 256 * i;
      int r = c >> 3, j = c & 7, jg = j ^ (r & 7);
      ASYNC16((char*)Bs + c * 16, (const char*)(Bt + (size_t)(n0 + r) * K_ + k0 + jg * 8));
    }
    __syncthreads();
#pragma unroll
    for (int ks = 0; ks < 2; ++ks) {
      bf16x8 afr[4], bfr[4];
#pragma unroll
      for (int im = 0; im < 4; ++im) {
        int r = wm + 16 * im + lr;
        afr[im] = *(const bf16x8*)((const char*)As + r * 128 + (((ks * 4 + hi) ^ (r & 7)) * 16));
      }
#pragma unroll
      for (int in = 0; in < 4; ++in) {
        int r = wn + 16 * in + lr;
        bfr[in] = *(const bf16x8*)((const char*)Bs + r * 128 + (((ks * 4 + hi) ^ (r & 7)) * 16));
      }
#pragma unroll
      for (int im = 0; im < 4; ++im)
#pragma unroll
        for (int in = 0; in < 4; ++in)
          acc[im][in] =
              __builtin_amdgcn_mfma_f32_16x16x32_bf16(afr[im], bfr[in], acc[im][in], 0, 0, 0);
    }
  }

#pragma unroll
  for (int im = 0; im < 4; ++im) {
#pragma unroll
    for (int in = 0; in < 4; ++in) {
      int c = n0 + wn + 16 * in + lr;
      float bv = biasf[c];
#pragma unroll
      for (int j = 0; j < 4; ++j) {
        int m = m0 + wm + 16 * im + 4 * hi + j;
        float z = acc[im][in][j] + bv;
        Out[(size_t)m * 2048 + c] = z / (1.f + __expf(-z));
      }
    }
  }
}

// ---------------------------------------------------------------------------
// Rotary in-place on Q,K head layout. Pair (d, d+64), angle col = d*16+h. fp32 cos/sin.
__global__ void rotary_kernel(bf16* __restrict__ Qg, bf16* __restrict__ Kg,
                              const float* __restrict__ cosp, const float* __restrict__ sinp) {
  int idx = blockIdx.x * 256 + threadIdx.x;  // B*NH*L*64 = 8388608
  int d = idx & 63;
  int l = (idx >> 6) & 2047;
  int bh = idx >> 17;
  int h = bh & 15;
  size_t base = ((size_t)bh * 2048 + l) * 128;
  int ang = l * 1024 + d * 16 + h;
  float c = cosp[ang], s = sinp[ang];
  float q1 = b2f(Qg[base + d]), q2 = b2f(Qg[base + d + 64]);
  Qg[base + d] = f2b(q1 * c + q2 * s);
  Qg[base + d + 64] = f2b(-q1 * s + q2 * c);
  float k1 = b2f(Kg[base + d]), k2 = b2f(Kg[base + d + 64]);
  Kg[base + d] = f2b(k1 * c + k2 * s);
  Kg[base + d + 64] = f2b(-k1 * s + k2 * c);
}

// ---------------------------------------------------------------------------
// Causal flash attention. Round 12: Q in registers (no Qs buffer; LDS 41KB ->
// 3 blocks/CU); K/V reg-staged with next-tile prefetch issued during compute
// (T14); Ps is wave-private -> lgkmcnt(0) instead of barrier before PV.
__global__ __launch_bounds__(256) void flash_kernel(const bf16* __restrict__ Qg,
                                                    const bf16* __restrict__ Kg,
                                                    const bf16* __restrict__ Vg,
                                                    bf16* __restrict__ Y) {
  __shared__ alignas(16) bf16 Ks[64 * 128];
  __shared__ alignas(16) bf16 Vt[128 * 64];
  __shared__ alignas(16) bf16 Ps[4 * 16 * 72];
  int tid = threadIdx.x, lane = tid & 63, w = tid >> 6;
  int lr = lane & 15, hi = lane >> 4;
  int it = 31 - (int)blockIdx.x;
  int bh = blockIdx.y;
  int b = bh >> 4, h = bh & 15;
  int q0 = it * 64;
  const bf16* Qb = Qg + (size_t)bh * 2048 * 128;
  const bf16* Kb = Kg + (size_t)bh * 2048 * 128;
  const bf16* Vb = Vg + (size_t)bh * 128 * 2048;
  const float NEG = -1.0e30f;
  int ar = 16 * w + lr;

  // Q fragments straight to registers (constant across jt; wave-private rows).
  bf16x8 qf[4];
#pragma unroll
  for (int ks = 0; ks < 4; ++ks)
    qf[ks] = *(const bf16x8*)(Qb + (size_t)(q0 + ar) * 128 + (ks * 4 + hi) * 8);

  // Prologue: issue K/V loads for jt=0 into staging registers.
  bf16x8 kreg[4], vreg[4];
#pragma unroll
  for (int i = 0; i < 4; ++i) {
    int c = tid + 256 * i;
    int rk = c >> 4, jk = (c & 15) ^ (rk & 7);
    kreg[i] = *(const bf16x8*)(Kb + (size_t)rk * 128 + jk * 8);
    int rv = c >> 3, jv = (c & 7) ^ (rv & 7);
    vreg[i] = *(const bf16x8*)(Vb + (size_t)rv * 2048 + jv * 8);
  }

  f32x4 o[8];
#pragma unroll
  for (int i = 0; i < 8; ++i) o[i] = (f32x4){0.f, 0.f, 0.f, 0.f};
  float m_i[4], l_i[4];
#pragma unroll
  for (int j = 0; j < 4; ++j) { m_i[j] = NEG; l_i[j] = 0.f; }
  const float scale = 0.08838834764831845f;  // 1/sqrt(128)

  for (int jt = 0; jt <= it; ++jt) {
    __syncthreads();  // all waves done reading Ks/Vt of previous tile
#pragma unroll
    for (int i = 0; i < 4; ++i) {
      int c = tid + 256 * i;
      *(bf16x8*)((char*)Ks + c * 16) = kreg[i];
      *(bf16x8*)((char*)Vt + c * 16) = vreg[i];
    }
    __syncthreads();  // staged tile visible to all waves

    // T14: issue next tile's global loads now; consumed at next iter's ds_write.
    if (jt < it) {
      int k0n = (jt + 1) * 64;
#pragma unroll
      for (int i = 0; i < 4; ++i) {
        int c = tid + 256 * i;
        int rk = c >> 4, jk = (c & 15) ^ (rk & 7);
        kreg[i] = *(const bf16x8*)(Kb + (size_t)(k0n + rk) * 128 + jk * 8);
        int rv = c >> 3, jv = (c & 7) ^ (rv & 7);
        vreg[i] = *(const bf16x8*)(Vb + (size_t)rv * 2048 + k0n + jv * 8);
      }
    }

    f32x4 sacc[4];
#pragma unroll
    for (int in = 0; in < 4; ++in) sacc[in] = (f32x4){0.f, 0.f, 0.f, 0.f};
#pragma unroll
    for (int ks = 0; ks < 4; ++ks) {
#pragma unroll
      for (int in = 0; in < 4; ++in) {
        int br = 16 * in + lr;
        bf16x8 bb =
            *(const bf16x8*)((const char*)Ks + br * 256 + (((ks * 4 + hi) ^ (br & 7)) * 16));
        sacc[in] = __builtin_amdgcn_mfma_f32_16x16x32_bf16(qf[ks], bb, sacc[in], 0, 0, 0);
      }
    }

    bool diag = (jt == it);
#pragma unroll
    for (int j = 0; j < 4; ++j) {
      float mx = NEG;
#pragma unroll
      for (int in = 0; in < 4; ++in) {
        float s = sacc[in][j] * scale;
        if (diag) {
          int qg = 16 * w + 4 * hi + j;
          int kg = 16 * in + lr;
          if (kg > qg) s = NEG;
        }
        sacc[in][j] = s;
        mx = fmaxf(mx, s);
      }
#pragma unroll
      for (int off = 1; off < 16; off <<= 1) mx = fmaxf(mx, __shfl_xor(mx, off));
      float mnew = fmaxf(m_i[j], mx);
      float alpha = __expf(m_i[j] - mnew);
      float rs = 0.f;
#pragma unroll
      for (int in = 0; in < 4; ++in) {
        float p = __expf(sacc[in][j] - mnew);
        sacc[in][j] = p;
        rs += p;
      }
#pragma unroll
      for (int off = 1; off < 16; off <<= 1) rs += __shfl_xor(rs, off);
      l_i[j] = alpha * l_i[j] + rs;
      m_i[j] = mnew;
#pragma unroll
      for (int inp = 0; inp < 8; ++inp) o[inp][j] *= alpha;
    }

#pragma unroll
    for (int j = 0; j < 4; ++j)
#pragma unroll
      for (int in = 0; in < 4; ++in)
        Ps[w * 1152 + (4 * hi + j) * 72 + 16 * in + lr] = f2b(sacc[in][j]);
    // Ps region is wave-private (w-indexed); only need this wave's LDS ops done.
    asm volatile("s_waitcnt lgkmcnt(0)" ::: "memory");

#pragma unroll
    for (int ko = 0; ko < 2; ++ko) {
      bf16x8 a = *(const bf16x8*)((const char*)Ps + (w * 1152 + lr * 72 + ko * 32 + hi * 8) * 2);
#pragma unroll
      for (int inp = 0; inp < 8; ++inp) {
        int br = 16 * inp + lr;
        bf16x8 bb =
            *(const bf16x8*)((const char*)Vt + br * 128 + (((ko * 4 + hi) ^ (br & 7)) * 16));
        o[inp] = __builtin_amdgcn_mfma_f32_16x16x32_bf16(a, bb, o[inp], 0, 0, 0);
      }
    }
  }

#pragma unroll
  for (int j = 0; j < 4; ++j) {
    int qg = q0 + 16 * w + 4 * hi + j;
    float inv = 1.f / l_i[j];
    size_t rowb = ((size_t)(b * 2048 + qg)) * 2048 + h * 128;
#pragma unroll
    for (int inp = 0; inp < 8; ++inp) {
      int dd = 16 * inp + lr;
      Y[rowb + dd] = f2b(o[inp][j] * inv);
    }
  }
}

// ---------------------------------------------------------------------------
extern "C" void kernel_launch(void* const* d_in, const int* in_sizes, int n_in,
                              void* d_out, int out_size, void* d_ws, size_t ws_size,
                              hipStream_t stream) {
  const float* x    = (const float*)d_in[0];  // 8192 x 2048
  const float* Wqkv = (const float*)d_in[1];  // 2048 x 6144
  const float* bqkv = (const float*)d_in[2];  // 6144
  const float* Wfc2 = (const float*)d_in[3];  // 2048 x 2048
  const float* bfc2 = (const float*)d_in[4];  // 2048
  const float* cosp = (const float*)d_in[5];  // 2048 x 1024
  const float* sinp = (const float*)d_in[6];  // 2048 x 1024
  float* out = (float*)d_out;

  // Workspace (bf16 elems), exactly 67,108,864 = 128 MB:
  //   [0, 16.78M):      Yg (flash out). WqkvT [0,12.58M) aliased pre-flash.
  //   [16.78M, 33.55M): Qg. Wfc2T [+0,+4.19M) aliased post-flash.
  //   [33.55M, 50.33M): Kg.
  //   [50.33M, 67.11M): Vg [bh][128][l].
  // x_bf16 (16.78M elems = 33.5 MB) parked in d_out (67 MB fp32, dead until fc2).
  bf16* ws = (bf16*)d_ws;
  bf16* Yg    = ws;
  bf16* WqkvT = ws;
  bf16* Qg    = ws + 16777216;
  bf16* Wfc2T = ws + 16777216;
  bf16* Kg    = ws + 33554432;
  bf16* Vg    = ws + 50331648;
  bf16* xb    = (bf16*)d_out;

  conv_bf16<<<8192, 256, 0, stream>>>(x, xb);
  transpose_conv<<<dim3(192, 64), dim3(32, 8), 0, stream>>>(Wqkv, WqkvT, 2048, 6144, 1);
  gemm_qkv<<<dim3(48, 64), 256, 0, stream>>>(xb, WqkvT, bqkv, Qg, Kg, Vg);
  rotary_kernel<<<32768, 256, 0, stream>>>(Qg, Kg, cosp, sinp);
  flash_kernel<<<dim3(32, 64), 256, 0, stream>>>(Qg, Kg, Vg, Yg);
  transpose_conv<<<dim3(64, 64), dim3(32, 8), 0, stream>>>(Wfc2, Wfc2T, 2048, 2048, 0);
  gemm_fc2<<<dim3(16, 64), 256, 0, stream>>>(Yg, Wfc2T, bfc2, out);
}

// Round 7
// 820.230 us; speedup vs baseline: 1.6442x; 1.0490x over previous
//
#include <hip/hip_runtime.h>
#include <hip/hip_bf16.h>
#include <cstdint>
#include <cstddef>

// B=4, L=2048, H=2048, NH=16, HD=128. Inputs/outputs fp32.
// Round 7:  XOR chunk swizzle on flash Qs/Ks/Vt — flash 612 -> ~370 us. CONFIRMED.
// Round 9:  bf16-pre-convert x; gemm_qkv ASYNC16 both operands. 527 -> 426 us.
// Round 10: WqkvT d-fast column permute + LDS-restaged V epilogue. total -> 863. CONFIRMED.
// Round 12: flash Q-in-registers (LDS 57->41KB) + T14 reg-staged K/V prefetch +
//           wave-local Ps wait. 362 -> 344 us only: occupancy stayed ~11%, the
//           exposed latency is INSIDE the iteration.
// Round 13: softmax cross-lane reduces were 32 serial ds_bpermute round-trips
//           per iter (__shfl_xor = LDS pipe on CDNA, ~60-120cyc each = most of
//           the ~6250 cyc/block-iter). Replaced with DPP butterflies (VALU-only:
//           quad_perm xor1, xor2, row_half_mirror, row_mirror) and batched the 4
//           independent j-chains per step. Zero LDS ops left in softmax.
// Workspace exactly 128 MB; x_bf16 parked in d_out.

typedef __attribute__((ext_vector_type(4))) float f32x4;
typedef __attribute__((ext_vector_type(8))) short bf16x8;
typedef __hip_bfloat16 bf16;

#define ASYNC16(lds, g)                                                                  \
  __builtin_amdgcn_global_load_lds((const __attribute__((address_space(1))) void*)(g),   \
                                   (__attribute__((address_space(3))) void*)(lds), 16, 0, 0)

__device__ __forceinline__ float b2f(bf16 v) { return __bfloat162float(v); }
__device__ __forceinline__ bf16 f2b(float v) { return __float2bfloat16(v); }
__device__ __forceinline__ short f2bs(float f) {
  bf16 h = __float2bfloat16(f);
  return __builtin_bit_cast(short, h);
}
__device__ __forceinline__ bf16x8 pack8(f32x4 a, f32x4 b) {
  bf16x8 r;
#pragma unroll
  for (int t = 0; t < 4; ++t) r[t] = f2bs(a[t]);
#pragma unroll
  for (int t = 0; t < 4; ++t) r[4 + t] = f2bs(b[t]);
  return r;
}

// DPP butterfly steps for a 16-lane reduce (VALU-only, no LDS):
// 0xB1 = quad_perm(1,0,3,2) [xor1], 0x4E = quad_perm(2,3,0,1) [xor2],
// 0x141 = row_half_mirror [quad<->quad], 0x140 = row_mirror [8<->8].
template <int CTRL>
__device__ __forceinline__ float dpp_bfly_max(float x) {
  int xi = __builtin_bit_cast(int, x);
  int yi = __builtin_amdgcn_update_dpp(xi, xi, CTRL, 0xF, 0xF, false);
  return fmaxf(x, __builtin_bit_cast(float, yi));
}
template <int CTRL>
__device__ __forceinline__ float dpp_bfly_add(float x) {
  int xi = __builtin_bit_cast(int, x);
  int yi = __builtin_amdgcn_update_dpp(xi, xi, CTRL, 0xF, 0xF, false);
  return x + __builtin_bit_cast(float, yi);
}

// ---------------------------------------------------------------------------
// Elementwise fp32 -> bf16, 8 elems/thread, fully coalesced.
__global__ void conv_bf16(const float* __restrict__ src, bf16* __restrict__ dst) {
  size_t i = ((size_t)blockIdx.x * 256 + threadIdx.x) * 8;
  f32x4 a0 = *(const f32x4*)(src + i);
  f32x4 a1 = *(const f32x4*)(src + i + 4);
  *(bf16x8*)(dst + i) = pack8(a0, a1);
}

// ---------------------------------------------------------------------------
// Transpose+convert fp32 (R x C) -> bf16 (C x R). perm=1: qkv column remap
// col = which*2048 + d*16 + h  ->  which*2048 + h*128 + d  (dst-row permute).
__global__ void transpose_conv(const float* __restrict__ src, bf16* __restrict__ dst,
                               int R, int C, int perm) {
  __shared__ float tile[32][33];
  int bx = blockIdx.x * 32, by = blockIdx.y * 32;
  int tx = threadIdx.x, ty = threadIdx.y;
  for (int i = ty; i < 32; i += 8) tile[i][tx] = src[(size_t)(by + i) * C + bx + tx];
  __syncthreads();
  for (int i = ty; i < 32; i += 8) {
    int c = bx + i;
    if (perm) {
      int cc = c & 2047;
      c = (c & ~2047) | (((cc & 15) << 7) | (cc >> 4));
    }
    dst[(size_t)c * R + by + tx] = f2b(tile[tx][i]);
  }
}

// ---------------------------------------------------------------------------
// QKV GEMM: C(8192,6144) = xb(8192,2048) * WqkvT(6144,2048)^T. 128x128, BK=64.
// Columns permuted (d-fast). Per n-tile: one (which,h), full d in [0,128).
__global__ __launch_bounds__(256) void gemm_qkv(const bf16* __restrict__ A,
                                                const bf16* __restrict__ Bt,
                                                const float* __restrict__ biasf,
                                                bf16* __restrict__ Qg, bf16* __restrict__ Kg,
                                                bf16* __restrict__ Vg) {
  __shared__ alignas(16) bf16 smem[2 * 128 * 64];  // As | Bs; reused as [128][128] for V restage
  bf16* As = smem;
  bf16* Bs = smem + 128 * 64;
  const int K_ = 2048;
  int tid = threadIdx.x, lane = tid & 63, w = tid >> 6;
  int lr = lane & 15, hi = lane >> 4;
  int wm = (w >> 1) * 64, wn = (w & 1) * 64;
  int m0 = blockIdx.y * 128, n0 = blockIdx.x * 128;
  f32x4 acc[4][4];
#pragma unroll
  for (int im = 0; im < 4; ++im)
#pragma unroll
    for (int in = 0; in < 4; ++in) acc[im][in] = (f32x4){0.f, 0.f, 0.f, 0.f};

  for (int k0 = 0; k0 < K_; k0 += 64) {
    __syncthreads();
#pragma unroll
    for (int i = 0; i < 4; ++i) {
      int c = tid + 256 * i;
      int r = c >> 3, j = c & 7, jg = j ^ (r & 7);
      ASYNC16((char*)As + c * 16, (const char*)(A + (size_t)(m0 + r) * K_ + k0 + jg * 8));
    }
#pragma unroll
    for (int i = 0; i < 4; ++i) {
      int c = tid + 256 * i;
      int r = c >> 3, j = c & 7, jg = j ^ (r & 7);
      ASYNC16((char*)Bs + c * 16, (const char*)(Bt + (size_t)(n0 + r) * K_ + k0 + jg * 8));
    }
    __syncthreads();

#pragma unroll
    for (int ks = 0; ks < 2; ++ks) {
      bf16x8 afr[4], bfr[4];
#pragma unroll
      for (int im = 0; im < 4; ++im) {
        int r = wm + 16 * im + lr;
        afr[im] = *(const bf16x8*)((const char*)As + r * 128 + (((ks * 4 + hi) ^ (r & 7)) * 16));
      }
#pragma unroll
      for (int in = 0; in < 4; ++in) {
        int r = wn + 16 * in + lr;
        bfr[in] = *(const bf16x8*)((const char*)Bs + r * 128 + (((ks * 4 + hi) ^ (r & 7)) * 16));
      }
#pragma unroll
      for (int im = 0; im < 4; ++im)
#pragma unroll
        for (int in = 0; in < 4; ++in)
          acc[im][in] =
              __builtin_amdgcn_mfma_f32_16x16x32_bf16(afr[im], bfr[in], acc[im][in], 0, 0, 0);
    }
  }

  // Epilogue. Block-uniform: which, h. d = wn + 16*in + lr (full [0,128) per tile).
  int which = n0 >> 11;
  int h = (n0 >> 7) & 15;
  int bq = m0 >> 11;
  int l_base = m0 & 2047;
  int bh = bq * 16 + h;
  float bv[4];
#pragma unroll
  for (int in = 0; in < 4; ++in)
    bv[in] = biasf[(which << 11) + ((wn + 16 * in + lr) << 4) + h];

  if (which < 2) {
    bf16* __restrict__ G = (which == 0) ? Qg : Kg;
#pragma unroll
    for (int im = 0; im < 4; ++im) {
#pragma unroll
      for (int in = 0; in < 4; ++in) {
        int d = wn + 16 * in + lr;
#pragma unroll
        for (int j = 0; j < 4; ++j) {
          int l = l_base + wm + 16 * im + 4 * hi + j;
          G[((size_t)bh * 2048 + l) * 128 + d] = f2b(acc[im][in][j] + bv[in]);
        }
      }
    }
  } else {
    // V: restage [128 d][128 l] through LDS (XOR'd 8-elem l-chunks), 16B stores.
    __syncthreads();
#pragma unroll
    for (int im = 0; im < 4; ++im)
#pragma unroll
      for (int in = 0; in < 4; ++in) {
        int d = wn + 16 * in + lr;
#pragma unroll
        for (int j = 0; j < 4; ++j) {
          int l = wm + 16 * im + 4 * hi + j;
          int slot = (l >> 3) ^ (d & 15);
          smem[d * 128 + slot * 8 + (l & 7)] = f2b(acc[im][in][j] + bv[in]);
        }
      }
    __syncthreads();
#pragma unroll
    for (int s = 0; s < 8; ++s) {
      int d = (tid >> 4) + 16 * s;
      int lc = tid & 15;
      int slot = lc ^ (d & 15);
      bf16x8 v = *(const bf16x8*)(smem + d * 128 + slot * 8);
      *(bf16x8*)(Vg + ((size_t)bh * 128 + d) * 2048 + l_base + lc * 8) = v;
    }
  }
}

// ---------------------------------------------------------------------------
// FC2 GEMM: Out(8192,2048) = Y(8192,2048) * Wfc2T(2048,2048)^T, bias+SiLU, fp32 out.
__global__ __launch_bounds__(256) void gemm_fc2(const bf16* __restrict__ A,
                                                const bf16* __restrict__ Bt,
                                                const float* __restrict__ biasf,
                                                float* __restrict__ Out) {
  __shared__ alignas(16) bf16 As[128 * 64];
  __shared__ alignas(16) bf16 Bs[128 * 64];
  const int K_ = 2048;
  int tid = threadIdx.x, lane = tid & 63, w = tid >> 6;
  int lr = lane & 15, hi = lane >> 4;
  int wm = (w >> 1) * 64, wn = (w & 1) * 64;
  int m0 = blockIdx.y * 128, n0 = blockIdx.x * 128;
  f32x4 acc[4][4];
#pragma unroll
  for (int im = 0; im < 4; ++im)
#pragma unroll
    for (int in = 0; in < 4; ++in) acc[im][in] = (f32x4){0.f, 0.f, 0.f, 0.f};

  for (int k0 = 0; k0 < K_; k0 += 64) {
    __syncthreads();
#pragma unroll
    for (int i = 0; i < 4; ++i) {
      int c = tid + 256 * i;
      int r = c >> 3, j = c & 7, jg = j ^ (r & 7);
      ASYNC16((char*)As + c * 16, (const char*)(A + (size_t)(m0 + r) * K_ + k0 + jg * 8));
    }
#pragma unroll
    for (int i = 0; i < 4; ++i) {
      int c = tid + 256 * i;
      int r = c >> 3, j = c & 7, jg = j ^ (r & 7);
      ASYNC16((char*)Bs + c * 16, (const char*)(Bt + (size_t)(n0 + r) * K_ + k0 + jg * 8));
    }
    __syncthreads();
#pragma unroll
    for (int ks = 0; ks < 2; ++ks) {
      bf16x8 afr[4], bfr[4];
#pragma unroll
      for (int im = 0; im < 4; ++im) {
        int r = wm + 16 * im + lr;
        afr[im] = *(const bf16x8*)((const char*)As + r * 128 + (((ks * 4 + hi) ^ (r & 7)) * 16));
      }
#pragma unroll
      for (int in = 0; in < 4; ++in) {
        int r = wn + 16 * in + lr;
        bfr[in] = *(const bf16x8*)((const char*)Bs + r * 128 + (((ks * 4 + hi) ^ (r & 7)) * 16));
      }
#pragma unroll
      for (int im = 0; im < 4; ++im)
#pragma unroll
        for (int in = 0; in < 4; ++in)
          acc[im][in] =
              __builtin_amdgcn_mfma_f32_16x16x32_bf16(afr[im], bfr[in], acc[im][in], 0, 0, 0);
    }
  }

#pragma unroll
  for (int im = 0; im < 4; ++im) {
#pragma unroll
    for (int in = 0; in < 4; ++in) {
      int c = n0 + wn + 16 * in + lr;
      float bv = biasf[c];
#pragma unroll
      for (int j = 0; j < 4; ++j) {
        int m = m0 + wm + 16 * im + 4 * hi + j;
        float z = acc[im][in][j] + bv;
        Out[(size_t)m * 2048 + c] = z / (1.f + __expf(-z));
      }
    }
  }
}

// ---------------------------------------------------------------------------
// Rotary in-place on Q,K head layout. Pair (d, d+64), angle col = d*16+h. fp32 cos/sin.
__global__ void rotary_kernel(bf16* __restrict__ Qg, bf16* __restrict__ Kg,
                              const float* __restrict__ cosp, const float* __restrict__ sinp) {
  int idx = blockIdx.x * 256 + threadIdx.x;  // B*NH*L*64 = 8388608
  int d = idx & 63;
  int l = (idx >> 6) & 2047;
  int bh = idx >> 17;
  int h = bh & 15;
  size_t base = ((size_t)bh * 2048 + l) * 128;
  int ang = l * 1024 + d * 16 + h;
  float c = cosp[ang], s = sinp[ang];
  float q1 = b2f(Qg[base + d]), q2 = b2f(Qg[base + d + 64]);
  Qg[base + d] = f2b(q1 * c + q2 * s);
  Qg[base + d + 64] = f2b(-q1 * s + q2 * c);
  float k1 = b2f(Kg[base + d]), k2 = b2f(Kg[base + d + 64]);
  Kg[base + d] = f2b(k1 * c + k2 * s);
  Kg[base + d + 64] = f2b(-k1 * s + k2 * c);
}

// ---------------------------------------------------------------------------
// Causal flash attention. Round 13: DPP-butterfly softmax reduces (no LDS).
__global__ __launch_bounds__(256) void flash_kernel(const bf16* __restrict__ Qg,
                                                    const bf16* __restrict__ Kg,
                                                    const bf16* __restrict__ Vg,
                                                    bf16* __restrict__ Y) {
  __shared__ alignas(16) bf16 Ks[64 * 128];
  __shared__ alignas(16) bf16 Vt[128 * 64];
  __shared__ alignas(16) bf16 Ps[4 * 16 * 72];
  int tid = threadIdx.x, lane = tid & 63, w = tid >> 6;
  int lr = lane & 15, hi = lane >> 4;
  int it = 31 - (int)blockIdx.x;
  int bh = blockIdx.y;
  int b = bh >> 4, h = bh & 15;
  int q0 = it * 64;
  const bf16* Qb = Qg + (size_t)bh * 2048 * 128;
  const bf16* Kb = Kg + (size_t)bh * 2048 * 128;
  const bf16* Vb = Vg + (size_t)bh * 128 * 2048;
  const float NEG = -1.0e30f;
  int ar = 16 * w + lr;

  // Q fragments straight to registers (constant across jt; wave-private rows).
  bf16x8 qf[4];
#pragma unroll
  for (int ks = 0; ks < 4; ++ks)
    qf[ks] = *(const bf16x8*)(Qb + (size_t)(q0 + ar) * 128 + (ks * 4 + hi) * 8);

  // Prologue: issue K/V loads for jt=0 into staging registers.
  bf16x8 kreg[4], vreg[4];
#pragma unroll
  for (int i = 0; i < 4; ++i) {
    int c = tid + 256 * i;
    int rk = c >> 4, jk = (c & 15) ^ (rk & 7);
    kreg[i] = *(const bf16x8*)(Kb + (size_t)rk * 128 + jk * 8);
    int rv = c >> 3, jv = (c & 7) ^ (rv & 7);
    vreg[i] = *(const bf16x8*)(Vb + (size_t)rv * 2048 + jv * 8);
  }

  f32x4 o[8];
#pragma unroll
  for (int i = 0; i < 8; ++i) o[i] = (f32x4){0.f, 0.f, 0.f, 0.f};
  float m_i[4], l_i[4];
#pragma unroll
  for (int j = 0; j < 4; ++j) { m_i[j] = NEG; l_i[j] = 0.f; }
  const float scale = 0.08838834764831845f;  // 1/sqrt(128)

  for (int jt = 0; jt <= it; ++jt) {
    __syncthreads();  // all waves done reading Ks/Vt of previous tile
#pragma unroll
    for (int i = 0; i < 4; ++i) {
      int c = tid + 256 * i;
      *(bf16x8*)((char*)Ks + c * 16) = kreg[i];
      *(bf16x8*)((char*)Vt + c * 16) = vreg[i];
    }
    __syncthreads();  // staged tile visible to all waves

    // T14: issue next tile's global loads now; consumed at next iter's ds_write.
    if (jt < it) {
      int k0n = (jt + 1) * 64;
#pragma unroll
      for (int i = 0; i < 4; ++i) {
        int c = tid + 256 * i;
        int rk = c >> 4, jk = (c & 15) ^ (rk & 7);
        kreg[i] = *(const bf16x8*)(Kb + (size_t)(k0n + rk) * 128 + jk * 8);
        int rv = c >> 3, jv = (c & 7) ^ (rv & 7);
        vreg[i] = *(const bf16x8*)(Vb + (size_t)rv * 2048 + k0n + jv * 8);
      }
    }

    f32x4 sacc[4];
#pragma unroll
    for (int in = 0; in < 4; ++in) sacc[in] = (f32x4){0.f, 0.f, 0.f, 0.f};
#pragma unroll
    for (int ks = 0; ks < 4; ++ks) {
#pragma unroll
      for (int in = 0; in < 4; ++in) {
        int br = 16 * in + lr;
        bf16x8 bb =
            *(const bf16x8*)((const char*)Ks + br * 256 + (((ks * 4 + hi) ^ (br & 7)) * 16));
        sacc[in] = __builtin_amdgcn_mfma_f32_16x16x32_bf16(qf[ks], bb, sacc[in], 0, 0, 0);
      }
    }

    // Softmax: scale/mask + register max over in, then DPP butterflies with the
    // four independent j-chains batched per step (no LDS, no shuffles).
    bool diag = (jt == it);
    float mxr[4], alpha[4], rsum[4];
#pragma unroll
    for (int j = 0; j < 4; ++j) {
      float mx = NEG;
#pragma unroll
      for (int in = 0; in < 4; ++in) {
        float s = sacc[in][j] * scale;
        if (diag) {
          int qg = 16 * w + 4 * hi + j;
          int kg = 16 * in + lr;
          if (kg > qg) s = NEG;
        }
        sacc[in][j] = s;
        mx = fmaxf(mx, s);
      }
      mxr[j] = mx;
    }
#pragma unroll
    for (int j = 0; j < 4; ++j) mxr[j] = dpp_bfly_max<0xB1>(mxr[j]);
#pragma unroll
    for (int j = 0; j < 4; ++j) mxr[j] = dpp_bfly_max<0x4E>(mxr[j]);
#pragma unroll
    for (int j = 0; j < 4; ++j) mxr[j] = dpp_bfly_max<0x141>(mxr[j]);
#pragma unroll
    for (int j = 0; j < 4; ++j) mxr[j] = dpp_bfly_max<0x140>(mxr[j]);

#pragma unroll
    for (int j = 0; j < 4; ++j) {
      float mnew = fmaxf(m_i[j], mxr[j]);
      alpha[j] = __expf(m_i[j] - mnew);
      m_i[j] = mnew;
      float r = 0.f;
#pragma unroll
      for (int in = 0; in < 4; ++in) {
        float p = __expf(sacc[in][j] - mnew);
        sacc[in][j] = p;
        r += p;
      }
      rsum[j] = r;
    }
#pragma unroll
    for (int j = 0; j < 4; ++j) rsum[j] = dpp_bfly_add<0xB1>(rsum[j]);
#pragma unroll
    for (int j = 0; j < 4; ++j) rsum[j] = dpp_bfly_add<0x4E>(rsum[j]);
#pragma unroll
    for (int j = 0; j < 4; ++j) rsum[j] = dpp_bfly_add<0x141>(rsum[j]);
#pragma unroll
    for (int j = 0; j < 4; ++j) rsum[j] = dpp_bfly_add<0x140>(rsum[j]);

#pragma unroll
    for (int j = 0; j < 4; ++j) {
      l_i[j] = alpha[j] * l_i[j] + rsum[j];
#pragma unroll
      for (int inp = 0; inp < 8; ++inp) o[inp][j] *= alpha[j];
    }

#pragma unroll
    for (int j = 0; j < 4; ++j)
#pragma unroll
      for (int in = 0; in < 4; ++in)
        Ps[w * 1152 + (4 * hi + j) * 72 + 16 * in + lr] = f2b(sacc[in][j]);
    // Ps region is wave-private (w-indexed); only need this wave's LDS ops done.
    asm volatile("s_waitcnt lgkmcnt(0)" ::: "memory");

#pragma unroll
    for (int ko = 0; ko < 2; ++ko) {
      bf16x8 a = *(const bf16x8*)((const char*)Ps + (w * 1152 + lr * 72 + ko * 32 + hi * 8) * 2);
#pragma unroll
      for (int inp = 0; inp < 8; ++inp) {
        int br = 16 * inp + lr;
        bf16x8 bb =
            *(const bf16x8*)((const char*)Vt + br * 128 + (((ko * 4 + hi) ^ (br & 7)) * 16));
        o[inp] = __builtin_amdgcn_mfma_f32_16x16x32_bf16(a, bb, o[inp], 0, 0, 0);
      }
    }
  }

#pragma unroll
  for (int j = 0; j < 4; ++j) {
    int qg = q0 + 16 * w + 4 * hi + j;
    float inv = 1.f / l_i[j];
    size_t rowb = ((size_t)(b * 2048 + qg)) * 2048 + h * 128;
#pragma unroll
    for (int inp = 0; inp < 8; ++inp) {
      int dd = 16 * inp + lr;
      Y[rowb + dd] = f2b(o[inp][j] * inv);
    }
  }
}

// ---------------------------------------------------------------------------
extern "C" void kernel_launch(void* const* d_in, const int* in_sizes, int n_in,
                              void* d_out, int out_size, void* d_ws, size_t ws_size,
                              hipStream_t stream) {
  const float* x    = (const float*)d_in[0];  // 8192 x 2048
  const float* Wqkv = (const float*)d_in[1];  // 2048 x 6144
  const float* bqkv = (const float*)d_in[2];  // 6144
  const float* Wfc2 = (const float*)d_in[3];  // 2048 x 2048
  const float* bfc2 = (const float*)d_in[4];  // 2048
  const float* cosp = (const float*)d_in[5];  // 2048 x 1024
  const float* sinp = (const float*)d_in[6];  // 2048 x 1024
  float* out = (float*)d_out;

  // Workspace (bf16 elems), exactly 67,108,864 = 128 MB:
  //   [0, 16.78M):      Yg (flash out). WqkvT [0,12.58M) aliased pre-flash.
  //   [16.78M, 33.55M): Qg. Wfc2T [+0,+4.19M) aliased post-flash.
  //   [33.55M, 50.33M): Kg.
  //   [50.33M, 67.11M): Vg [bh][128][l].
  // x_bf16 (16.78M elems = 33.5 MB) parked in d_out (67 MB fp32, dead until fc2).
  bf16* ws = (bf16*)d_ws;
  bf16* Yg    = ws;
  bf16* WqkvT = ws;
  bf16* Qg    = ws + 16777216;
  bf16* Wfc2T = ws + 16777216;
  bf16* Kg    = ws + 33554432;
  bf16* Vg    = ws + 50331648;
  bf16* xb    = (bf16*)d_out;

  conv_bf16<<<8192, 256, 0, stream>>>(x, xb);
  transpose_conv<<<dim3(192, 64), dim3(32, 8), 0, stream>>>(Wqkv, WqkvT, 2048, 6144, 1);
  gemm_qkv<<<dim3(48, 64), 256, 0, stream>>>(xb, WqkvT, bqkv, Qg, Kg, Vg);
  rotary_kernel<<<32768, 256, 0, stream>>>(Qg, Kg, cosp, sinp);
  flash_kernel<<<dim3(32, 64), 256, 0, stream>>>(Qg, Kg, Vg, Yg);
  transpose_conv<<<dim3(64, 64), dim3(32, 8), 0, stream>>>(Wfc2, Wfc2T, 2048, 2048, 0);
  gemm_fc2<<<dim3(16, 64), 256, 0, stream>>>(Yg, Wfc2T, bfc2, out);
}